// Round 12
// baseline (227.547 us; speedup 1.0000x reference)
//
#include <hip/hip_runtime.h>
#include <hip/hip_bf16.h>

typedef __attribute__((ext_vector_type(8))) short short8;
typedef __attribute__((ext_vector_type(4))) float f32x4;
typedef __attribute__((ext_vector_type(16))) float f32x16;

#define N_EMBED 2048
#define N_HEAD 16
#define BB 2
#define SS 2048
#define NTOK (BB*SS)          // 4096
#define HD2 192               // absorbed head dim: 128 latent + 64 rope
#define QSTR 3072             // q_all row stride = 16*192

__device__ __forceinline__ unsigned short f2bf(float f) {
    unsigned int b = __builtin_bit_cast(unsigned int, f);
    b += 0x7fffu + ((b >> 16) & 1u);
    return (unsigned short)(b >> 16);
}
__device__ __forceinline__ float bf2f(unsigned short u) {
    unsigned int b = ((unsigned int)u) << 16;
    return __builtin_bit_cast(float, b);
}

#define GLOAD_LDS16(gsrc, ldst) __builtin_amdgcn_global_load_lds( \
    (const __attribute__((address_space(1))) void*)(gsrc), \
    (__attribute__((address_space(3))) void*)(ldst), 16, 0, 0)

#define ROPE_COEF (-0.28782313662425575f)  // -ln(10000)/32

// ---------------- prep: layouts + bf16 copies + rope table ----------------
__global__ __launch_bounds__(256) void prep_kernel(
    const float* __restrict__ Wdkv, const float* __restrict__ Wdq, const float* __restrict__ Wkr,
    const float* __restrict__ Wqc, const float* __restrict__ Wqr,
    const float* __restrict__ Wuk, const float* __restrict__ Wuv, const float* __restrict__ Wo,
    unsigned short* __restrict__ WcatT, unsigned short* __restrict__ Wq2T,
    unsigned short* __restrict__ WqcB, unsigned short* __restrict__ WukB,
    unsigned short* __restrict__ WuvB, unsigned short* __restrict__ WoT,
    float2* __restrict__ rope_tab) {
    __shared__ float tile[64][65];
    const int bid = blockIdx.x, tid = threadIdx.x;
    if (bid < 2560) {                       // WcatT [320][2048]
        int i = bid * 256 + tid;
        int n = i >> 11, k = i & 2047;
        float v;
        if (n < 128)      v = Wdkv[k * 128 + n];
        else if (n < 256) v = Wdq[k * 128 + (n - 128)];
        else              v = Wkr[k * 64 + (n - 256)];
        WcatT[i] = f2bf(v);
    } else if (bid < 3072) {                // Wq2T rope rows: [h][64 jr][128 k]
        int i = (bid - 2560) * 256 + tid;
        int h = i >> 13, jr = (i >> 7) & 63, k = i & 127;
        Wq2T[((size_t)(h * HD2 + 128 + jr)) * 128 + k] = f2bf(Wqr[(h * 128 + k) * 64 + jr]);
    } else if (bid < 3584) {                // WqcB plain copy [16][128][64]
        int i = (bid - 3072) * 256 + tid;
        WqcB[i] = f2bf(Wqc[i]);
    } else if (bid < 4096) {                // WukB plain copy
        int i = (bid - 3584) * 256 + tid;
        WukB[i] = f2bf(Wuk[i]);
    } else if (bid < 5120) {                // WuvB plain copy [16][128][128]
        int i = (bid - 4096) * 256 + tid;
        WuvB[i] = f2bf(Wuv[i]);
    } else if (bid < 6144) {                // WoT [2048][2048] tiled transpose
        int tb = bid - 5120;
        const int k0 = (tb & 31) * 64, n0 = (tb >> 5) * 64;
        const int tr = tid >> 4, tc = (tid & 15) * 4;
#pragma unroll
        for (int it = 0; it < 4; ++it) {
            int r = it * 16 + tr;
            float4 v = *(const float4*)(Wo + (size_t)(k0 + r) * 2048 + n0 + tc);
            tile[r][tc] = v.x; tile[r][tc + 1] = v.y; tile[r][tc + 2] = v.z; tile[r][tc + 3] = v.w;
        }
        __syncthreads();
#pragma unroll
        for (int it = 0; it < 4; ++it) {
            int r = it * 16 + tr;
            ushort4 o;
            o.x = f2bf(tile[tc][r]); o.y = f2bf(tile[tc + 1][r]);
            o.z = f2bf(tile[tc + 2][r]); o.w = f2bf(tile[tc + 3][r]);
            *(ushort4*)(WoT + (size_t)(n0 + r) * 2048 + k0 + tc) = o;
        }
    } else {                                // rope table [SS][32]
        int i = (bid - 6144) * 256 + tid;
        int pos = i >> 5, j = i & 31;
        float freq = __expf(ROPE_COEF * (float)j);
        float a = (float)pos * freq;
        float s, c;
        __sincosf(a, &s, &c);
        rope_tab[i] = make_float2(c, s);
    }
}

// ---------------- fused weight GEMMs: wqk (bid 0-15) + weff (bid 16-271) ----------------
__global__ __launch_bounds__(256) void weights2_kernel(
    const unsigned short* __restrict__ WqcB,   // [16][128][64]
    const unsigned short* __restrict__ WukB,   // [16][128][64]
    unsigned short* __restrict__ Wq2T,         // [3072][128]
    const unsigned short* __restrict__ WoT,    // [2048][2048]
    const unsigned short* __restrict__ WuvB,   // [16][128][128]
    unsigned short* __restrict__ WeffT) {      // [2048][2048]
    __shared__ __align__(16) unsigned short As[2][128][32];
    __shared__ __align__(16) unsigned short Bs[2][128][32];
    const int bid = blockIdx.x;
    const int tid = threadIdx.x, wave = tid >> 6, lane = tid & 63;
    const int wr = wave >> 1, wc = wave & 1;
    const int lg = lane >> 4, lr = lane & 15;
    if (bid < 16) {
        // W_qk[h] = W_qc[h] @ W_uk[h]^T  -> Wq2T rows h*192+[0,128)
        const int h = bid;
        const unsigned short* A = WqcB + (size_t)h * 8192;
        const unsigned short* Bt = WukB + (size_t)h * 8192;
        f32x4 acc[4][4] = {};
#pragma unroll
        for (int kk = 0; kk < 2; ++kk) {
            short8 af[4], bfr[4];
#pragma unroll
            for (int i = 0; i < 4; i++) af[i] = *(const short8*)(A + (wr * 64 + i * 16 + lr) * 64 + kk * 32 + lg * 8);
#pragma unroll
            for (int j = 0; j < 4; j++) bfr[j] = *(const short8*)(Bt + (wc * 64 + j * 16 + lr) * 64 + kk * 32 + lg * 8);
#pragma unroll
            for (int i = 0; i < 4; i++)
#pragma unroll
                for (int j = 0; j < 4; j++)
                    acc[i][j] = __builtin_amdgcn_mfma_f32_16x16x32_bf16(af[i], bfr[j], acc[i][j], 0, 0, 0);
        }
#pragma unroll
        for (int i = 0; i < 4; i++)
#pragma unroll
            for (int j = 0; j < 4; j++)
#pragma unroll
                for (int r = 0; r < 4; r++) {
                    int row = wr * 64 + i * 16 + lg * 4 + r;   // k_in
                    int col = wc * 64 + j * 16 + lr;           // latent k'
                    Wq2T[((size_t)(h * HD2 + col)) * 128 + row] = f2bf(acc[i][j][r]);
                }
    } else {
        // W_effT[e][h*128+dl] = sum_dh WuvB[h][dl][dh] * WoT[e][h*128+dh]
        const int et = (bid - 16) & 15, h = (bid - 16) >> 4;
        const unsigned short* A = WoT + (size_t)et * 128 * 2048 + h * 128;
        const unsigned short* Bt = WuvB + (size_t)h * 16384;
        f32x4 acc[4][4] = {};
        auto stage = [&](int k0, int buf) {
#pragma unroll
            for (int it = 0; it < 2; ++it) {
                int e = (tid + it * 256) * 8;
                GLOAD_LDS16(A + (size_t)(e >> 5) * 2048 + k0 + (e & 31), &As[buf][0][0] + e);
            }
#pragma unroll
            for (int it = 0; it < 2; ++it) {
                int e = (tid + it * 256) * 8;
                GLOAD_LDS16(Bt + (size_t)(e >> 5) * 128 + k0 + (e & 31), &Bs[buf][0][0] + e);
            }
        };
        stage(0, 0);
        __syncthreads();
        for (int t = 0; t < 4; ++t) {
            const int cur = t & 1;
            if (t + 1 < 4) stage((t + 1) * 32, cur ^ 1);
            short8 af[4], bfr[4];
#pragma unroll
            for (int i = 0; i < 4; i++) af[i] = *(const short8*)&As[cur][wr * 64 + i * 16 + lr][lg * 8];
#pragma unroll
            for (int j = 0; j < 4; j++) bfr[j] = *(const short8*)&Bs[cur][wc * 64 + j * 16 + lr][lg * 8];
#pragma unroll
            for (int i = 0; i < 4; i++)
#pragma unroll
                for (int j = 0; j < 4; j++)
                    acc[i][j] = __builtin_amdgcn_mfma_f32_16x16x32_bf16(af[i], bfr[j], acc[i][j], 0, 0, 0);
            __syncthreads();
        }
#pragma unroll
        for (int i = 0; i < 4; i++)
#pragma unroll
            for (int j = 0; j < 4; j++)
#pragma unroll
                for (int r = 0; r < 4; r++) {
                    int row = et * 128 + wr * 64 + i * 16 + lg * 4 + r;   // e
                    int col = wc * 64 + j * 16 + lr;                      // dl
                    WeffT[(size_t)row * 2048 + h * 128 + col] = f2bf(acc[i][j][r]);
                }
    }
}

// ---------------- fused: ckv_t transpose (bid<128) + rope_k (bid 128-639) ----------------
__global__ __launch_bounds__(256) void ckvt_ropek_kernel(
    unsigned short* __restrict__ g1, unsigned short* __restrict__ ckv_t,
    const float2* __restrict__ tab) {
    __shared__ unsigned short tile[64][65];
    const int bid = blockIdx.x, tid = threadIdx.x;
    if (bid < 128) {                        // ckv_t[b][dl][s] = g1[b*SS+s][dl]
        const int s0 = (bid & 31) * 64, d0 = ((bid >> 5) & 1) * 64, b = bid >> 6;
        const int tr = tid >> 4, tc = (tid & 15) * 4;
#pragma unroll
        for (int it = 0; it < 4; ++it) {
            int r = it * 16 + tr;
            *(ushort4*)&tile[r][tc] = *(const ushort4*)(g1 + (size_t)(b * SS + s0 + r) * 320 + d0 + tc);
        }
        __syncthreads();
#pragma unroll
        for (int it = 0; it < 4; ++it) {
            int r = it * 16 + tr;
            ushort4 o;
            o.x = tile[tc][r]; o.y = tile[tc + 1][r]; o.z = tile[tc + 2][r]; o.w = tile[tc + 3][r];
            *(ushort4*)(ckv_t + ((size_t)b * 128 + d0 + r) * 2048 + s0 + tc) = o;
        }
    } else {                                // rope_k: NTOK*32 elements
        int i = (bid - 128) * 256 + tid;
        int j = i & 31, row = i >> 5;
        int pos = row & (SS - 1);
        float2 cs = tab[(pos << 5) | j];
        unsigned short* p = g1 + (size_t)row * 320 + 256 + 2 * j;
        float x0 = bf2f(p[0]), x1 = bf2f(p[1]);
        p[0] = f2bf(x0 * cs.x - x1 * cs.y);
        p[1] = f2bf(x0 * cs.y + x1 * cs.x);
    }
}

// ---------------- q-projection with fused rope epilogue ----------------
// q_all[tok][h*192+c] = g1[tok][128+k]·Wq2T[h*192+c][k]; rope applied in-register
// to cols c>=128 via lane-pair shfl (pairs are adjacent lanes since col = ...+lr).
__global__ __launch_bounds__(256) void gemm_q_kernel(
    const unsigned short* __restrict__ A,      // g1+128, lda 320
    const unsigned short* __restrict__ Bt,     // Wq2T [3072][128]
    unsigned short* __restrict__ C,            // q_all [NTOK][3072]
    const float2* __restrict__ tab) {
    constexpr int BM = 128, BN = 128, BK = 32;
    __shared__ __align__(16) unsigned short As[2][BM][BK];
    __shared__ __align__(16) unsigned short Bs[2][BN][BK];
    const int tid = threadIdx.x, wave = tid >> 6, lane = tid & 63;
    const int wr = wave >> 1, wc = wave & 1;
    const int lg = lane >> 4, lr = lane & 15;
    const int m0 = blockIdx.y * BM, n0 = blockIdx.x * BN;

    f32x4 acc[4][4] = {};
    auto stage = [&](int k0, int buf) {
#pragma unroll
        for (int it = 0; it < 2; ++it) {
            int e = (tid + it * 256) * 8;
            GLOAD_LDS16(A + (size_t)(m0 + (e >> 5)) * 320 + k0 + (e & 31), &As[buf][0][0] + e);
        }
#pragma unroll
        for (int it = 0; it < 2; ++it) {
            int e = (tid + it * 256) * 8;
            GLOAD_LDS16(Bt + (size_t)(n0 + (e >> 5)) * 128 + k0 + (e & 31), &Bs[buf][0][0] + e);
        }
    };
    stage(0, 0);
    __syncthreads();
    for (int t = 0; t < 4; ++t) {
        const int cur = t & 1;
        if (t + 1 < 4) stage((t + 1) * BK, cur ^ 1);
        short8 af[4], bfr[4];
#pragma unroll
        for (int i = 0; i < 4; i++) af[i] = *(const short8*)&As[cur][wr * 64 + i * 16 + lr][lg * 8];
#pragma unroll
        for (int j = 0; j < 4; j++) bfr[j] = *(const short8*)&Bs[cur][wc * 64 + j * 16 + lr][lg * 8];
#pragma unroll
        for (int i = 0; i < 4; i++)
#pragma unroll
            for (int j = 0; j < 4; j++)
                acc[i][j] = __builtin_amdgcn_mfma_f32_16x16x32_bf16(af[i], bfr[j], acc[i][j], 0, 0, 0);
        __syncthreads();
    }
#pragma unroll
    for (int i = 0; i < 4; i++)
#pragma unroll
        for (int j = 0; j < 4; j++) {
            const int colb = n0 + wc * 64 + j * 16;        // frag base (mult of 16)
            const int c6 = colb >> 6;
            const int h = (c6 * 43) >> 7;                  // colb/192 for colb<3072
            const int ch = colb - h * 192;                 // uniform per frag
#pragma unroll
            for (int r = 0; r < 4; r++) {
                int row = m0 + wr * 64 + i * 16 + lg * 4 + r;
                int col = colb + lr;
                float val = acc[i][j][r];
                if (ch >= 128) {                           // roped range (frag-uniform)
                    float partner = __shfl_xor(val, 1);
                    int jr = (ch + lr - 128) >> 1;         // pair index, same for lane pair
                    float2 cs = tab[((row & (SS - 1)) << 5) | jr];
                    val = (lr & 1) ? (partner * cs.y + val * cs.x)
                                   : (val * cs.x - partner * cs.y);
                }
                C[(size_t)row * QSTR + col] = f2bf(val);
            }
        }
}

// Latent GEMM with f32 A (conversion folded in)
__global__ __launch_bounds__(256) void gemm_lat_kernel(
    const float* __restrict__ A,               // [NTOK][2048] f32
    const unsigned short* __restrict__ Bt,     // WcatT [320][2048]
    unsigned short* __restrict__ C) {          // g1 [NTOK][320]
    constexpr int BM = 128, BN = 64, BK = 32, K = 2048;
    __shared__ __align__(16) unsigned short As[2][BM][BK];
    __shared__ __align__(16) unsigned short Bs[2][BN][BK];
    constexpr int WN = BN / 2, FM = 4, FN = WN / 16;
    const int tid = threadIdx.x, wave = tid >> 6, lane = tid & 63;
    const int wr = wave >> 1, wc = wave & 1;
    const int lg = lane >> 4, lr = lane & 15;
    const int m0 = blockIdx.y * BM, n0 = blockIdx.x * BN;

    f32x4 acc[FM][FN] = {};
    const int ar = (tid * 16) >> 5, ac = (tid * 16) & 31;

    float4 a4[4];
    auto loadA = [&](int k0) {
        const float* src = A + (size_t)(m0 + ar) * K + k0 + ac;
#pragma unroll
        for (int i = 0; i < 4; ++i) a4[i] = *(const float4*)(src + i * 4);
    };
    auto writeA = [&](int buf) {
        unsigned int pk[8];
        const float* f = (const float*)a4;
#pragma unroll
        for (int i = 0; i < 8; ++i)
            asm("v_cvt_pk_bf16_f32 %0, %1, %2" : "=v"(pk[i]) : "v"(f[2 * i]), "v"(f[2 * i + 1]));
        *(uint4*)&As[buf][ar][ac]     = make_uint4(pk[0], pk[1], pk[2], pk[3]);
        *(uint4*)&As[buf][ar][ac + 8] = make_uint4(pk[4], pk[5], pk[6], pk[7]);
    };
    auto stageB = [&](int k0, int buf) {
        int e = tid * 8;
        GLOAD_LDS16(Bt + (size_t)(n0 + (e >> 5)) * K + k0 + (e & 31), &Bs[buf][0][0] + e);
    };

    loadA(0); stageB(0, 0); writeA(0);
    __syncthreads();
    constexpr int nk = K / BK;
    for (int t = 0; t < nk; ++t) {
        const int cur = t & 1;
        if (t + 1 < nk) { loadA((t + 1) * BK); stageB((t + 1) * BK, cur ^ 1); }
        short8 af[FM], bfr[FN];
#pragma unroll
        for (int i = 0; i < FM; i++) af[i] = *(const short8*)&As[cur][wr * 64 + i * 16 + lr][lg * 8];
#pragma unroll
        for (int j = 0; j < FN; j++) bfr[j] = *(const short8*)&Bs[cur][wc * WN + j * 16 + lr][lg * 8];
#pragma unroll
        for (int i = 0; i < FM; i++)
#pragma unroll
            for (int j = 0; j < FN; j++)
                acc[i][j] = __builtin_amdgcn_mfma_f32_16x16x32_bf16(af[i], bfr[j], acc[i][j], 0, 0, 0);
        if (t + 1 < nk) writeA(cur ^ 1);
        __syncthreads();
    }
#pragma unroll
    for (int i = 0; i < FM; i++)
#pragma unroll
        for (int j = 0; j < FN; j++)
#pragma unroll
            for (int r = 0; r < 4; r++) {
                int row = m0 + wr * 64 + i * 16 + lg * 4 + r;
                int col = n0 + wc * WN + j * 16 + lr;
                C[(size_t)row * 320 + col] = f2bf(acc[i][j][r]);
            }
}

// ---------------- out-proj: 128x256 deep-pipelined GEMM (T2+T3+T4+T5) ----------------
__global__ __launch_bounds__(512, 2) void gemm_out_kernel(
    const unsigned short* __restrict__ Ag,     // attn [4096][2048]
    const unsigned short* __restrict__ Bg,     // WeffT [2048][2048]
    float* __restrict__ C) {
    __shared__ __align__(16) unsigned short As[3][128][64];
    __shared__ __align__(16) unsigned short Bs[3][256][64];
    const int tid = threadIdx.x, wave = tid >> 6, lane = tid & 63;
    const int wr = wave >> 2, wc = wave & 3;
    const int lg = lane >> 4, lr = lane & 15;
    int id = blockIdx.y * gridDim.x + blockIdx.x;      // grid (8, 32) = 256
    int swz = (id & 7) * 32 + (id >> 3);               // bijective XCD grouping
    const int n0 = (swz & 7) * 256;
    const int m0 = (swz >> 3) * 128;

    f32x4 acc[4][4] = {};

    auto STAGE = [&](int kt, int buf) {
        const int k0 = kt * 64;
#pragma unroll
        for (int it = 0; it < 2; ++it) {               // A: 128 rows x 8 chunks
            int cid = tid + it * 512;
            int row = cid >> 3, slot = cid & 7;
            int csrc = slot ^ (row & 7);
            GLOAD_LDS16(Ag + (size_t)(m0 + row) * 2048 + k0 + csrc * 8, &As[buf][0][0] + cid * 8);
        }
#pragma unroll
        for (int it = 0; it < 4; ++it) {               // B: 256 rows x 8 chunks
            int cid = tid + it * 512;
            int row = cid >> 3, slot = cid & 7;
            int csrc = slot ^ (row & 7);
            GLOAD_LDS16(Bg + (size_t)(n0 + row) * 2048 + k0 + csrc * 8, &Bs[buf][0][0] + cid * 8);
        }
    };
    auto compute = [&](int buf) {
#pragma unroll
        for (int ks = 0; ks < 2; ++ks) {
            const int ca = ((ks * 4 + lg) ^ (lr & 7)) * 8;   // swizzled read chunk
            short8 af[4], bfr[4];
#pragma unroll
            for (int i = 0; i < 4; i++) af[i] = *(const short8*)&As[buf][wr * 64 + i * 16 + lr][ca];
#pragma unroll
            for (int j = 0; j < 4; j++) bfr[j] = *(const short8*)&Bs[buf][wc * 64 + j * 16 + lr][ca];
            __builtin_amdgcn_s_setprio(1);
#pragma unroll
            for (int i = 0; i < 4; i++)
#pragma unroll
                for (int j = 0; j < 4; j++)
                    acc[i][j] = __builtin_amdgcn_mfma_f32_16x16x32_bf16(af[i], bfr[j], acc[i][j], 0, 0, 0);
            __builtin_amdgcn_s_setprio(0);
        }
    };

    STAGE(0, 0); STAGE(1, 1); STAGE(2, 2);             // 18 loads in flight
    for (int t = 0; t < 30; ++t) {
        asm volatile("s_waitcnt vmcnt(12)" ::: "memory");
        __builtin_amdgcn_s_barrier();
        asm volatile("" ::: "memory");
        compute(t % 3);
        asm volatile("" ::: "memory");
        __builtin_amdgcn_s_barrier();
        if (t < 29) STAGE(t + 3, t % 3);
    }
    asm volatile("s_waitcnt vmcnt(6)" ::: "memory");
    __builtin_amdgcn_s_barrier();
    asm volatile("" ::: "memory");
    compute(0);
    asm volatile("" ::: "memory");
    __builtin_amdgcn_s_barrier();
    asm volatile("s_waitcnt vmcnt(0)" ::: "memory");
    __builtin_amdgcn_s_barrier();
    asm volatile("" ::: "memory");
    compute(1);

#pragma unroll
    for (int i = 0; i < 4; i++)
#pragma unroll
        for (int j = 0; j < 4; j++)
#pragma unroll
            for (int r = 0; r < 4; r++) {
                int row = m0 + wr * 64 + i * 16 + lg * 4 + r;
                int col = n0 + wc * 64 + j * 16 + lr;
                C[(size_t)row * 2048 + col] = acc[i][j][r];
            }
}

// ---------------- flash attention v9: absorbed, 2 heads/block, split-pair balance ----------------
__global__ __launch_bounds__(512) void mla_attn_kernel(
    const unsigned short* __restrict__ q_all,   // [NTOK][3072]: per head [qtil(128)|qrope(64)]
    const unsigned short* __restrict__ g1,      // [NTOK][320]: ckv 0..127, roped k_r 256..319
    const unsigned short* __restrict__ ckv_t,   // [2][128][2048]
    unsigned short* __restrict__ attn_out,      // [NTOK][2048] (o_lat)
    unsigned short* __restrict__ partOb,        // [256 pair][2 side][128 q][128 d] bf16
    float* __restrict__ partL,
    float* __restrict__ partM) {
    __shared__ __align__(16) char smem[81920];
    auto Ks = (unsigned short (*)[64][192])smem;             // [2][64][192], chunk-swizzled
    auto Vs = (unsigned short (*)[128][64])(smem + 49152);   // [2][128][64], chunk-swizzled

    const int id = blockIdx.x;
    const int xcd = id & 7, loc = id >> 3;
    const int hp = 2 * xcd + (loc >> 4);        // head-pair 0..15
    const int s2 = loc & 15;
    const bool roleA = s2 < 8;
    const int qb = roleA ? s2 : s2 - 8;
    const int hiqb = 15 - qb, xsp = 15 - 2 * qb;
    const int b = hp >> 3;
    const int tid = threadIdx.x, wave = tid >> 6, lane = tid & 63;
    const int wg = wave & 3, hsel = wave >> 2;
    const int h = (hp & 7) * 2 + hsel;
    const int bh = b * 16 + h;
    const int pairIdx = bh * 8 + qb;
    const int ql = lane & 31, hb = lane >> 5;
    const int kvB = b * SS;
    const float sc2 = 0.12751744f;   // (1/sqrt(128)) * log2(e)
    const int xh = ql & 7;

    uint4 vreg[2];
    auto stageK = [&](int t, int bufi) {
#pragma unroll
        for (int it = 0; it < 3; ++it) {
            int cid = tid + it * 512;
            int r = cid / 24, s = cid - r * 24;
            int c = s ^ (r & 7);
            int col = (c < 16) ? c * 8 : 256 + (c - 16) * 8;
            GLOAD_LDS16(g1 + (size_t)(kvB + t * 64 + r) * 320 + col,
                        &Ks[bufi][0][0] + cid * 8);
        }
    };
    auto loadV = [&](int t) {
#pragma unroll
        for (int it = 0; it < 2; ++it) {
            int e = tid * 8 + it * 4096;
            vreg[it] = *(const uint4*)(ckv_t + ((size_t)b * 128 + (e >> 6)) * 2048 + t * 64 + (e & 63));
        }
    };
    auto writeV = [&](int bufi) {
#pragma unroll
        for (int it = 0; it < 2; ++it) {
            int e = tid * 8 + it * 4096;
            int d = e >> 6, j = (e & 63) >> 3;
            *(uint4*)&Vs[bufi][d][(j ^ (d & 7)) * 8] = vreg[it];
        }
    };

    auto run = [&](int q0, int t0, int cnt, bool direct, int side) {
        __syncthreads();
        const int q0w = q0 + wg * 32;
        const int qg = q0w + ql;

        short8 qf[12];
        {
            const unsigned short* qp = q_all + (size_t)(kvB + qg) * QSTR + h * HD2 + hb * 8;
#pragma unroll
            for (int ss = 0; ss < 12; ++ss) qf[ss] = *(const short8*)(qp + 16 * ss);
        }
        f32x16 o[4] = {};
        float m_raw = -3e38f, mb = 0.f, l_r = 0.f;

        stageK(t0, 0);
        loadV(t0);
        writeV(0);
        __syncthreads();

        for (int tt = 0; tt < cnt; ++tt) {
            const int t = t0 + tt;
            const int cur = tt & 1;
            if (tt + 1 < cnt) { stageK(t + 1, cur ^ 1); loadV(t + 1); }
            {
                f32x16 p0 = {}, p1 = {};
                __builtin_amdgcn_s_setprio(1);
#pragma unroll
                for (int ss = 0; ss < 12; ++ss) {
                    int pc = (((2 * ss + hb) ^ xh) << 3);
                    short8 k0 = *(const short8*)&Ks[cur][ql][pc];
                    short8 k1 = *(const short8*)&Ks[cur][32 + ql][pc];
                    p0 = __builtin_amdgcn_mfma_f32_32x32x16_bf16(k0, qf[ss], p0, 0, 0, 0);
                    p1 = __builtin_amdgcn_mfma_f32_32x32x16_bf16(k1, qf[ss], p1, 0, 0, 0);
                }
                __builtin_amdgcn_s_setprio(0);
                const int kv0 = t * 64;
                if (kv0 + 63 > q0w) {
#pragma unroll
                    for (int r = 0; r < 16; ++r) {
                        int kvg = kv0 + (r & 3) + 8 * (r >> 2) + 4 * hb;
                        if (kvg > qg) p0[r] = -3e38f;
                        if (kvg + 32 > qg) p1[r] = -3e38f;
                    }
                }
                float pm = -3e38f;
#pragma unroll
                for (int r = 0; r < 16; ++r) pm = fmaxf(pm, fmaxf(p0[r], p1[r]));
                pm = fmaxf(pm, __shfl_xor(pm, 32));
                if (__any(pm > m_raw + 64.f)) {   // defer-max (T13)
                    float mn = fmaxf(m_raw, pm);
                    float alpha = exp2f((m_raw - mn) * sc2);
                    m_raw = mn; mb = mn * sc2;
                    l_r *= alpha;
#pragma unroll
                    for (int dt = 0; dt < 4; ++dt)
#pragma unroll
                        for (int r = 0; r < 16; ++r) o[dt][r] *= alpha;
                }
                float ps = 0.f;
#pragma unroll
                for (int r = 0; r < 16; ++r) {
                    p0[r] = exp2f(__builtin_fmaf(p0[r], sc2, -mb));
                    p1[r] = exp2f(__builtin_fmaf(p1[r], sc2, -mb));
                    ps += p0[r] + p1[r];
                }
                l_r += ps;
                unsigned int pk0[8], pk1[8];
#pragma unroll
                for (int i = 0; i < 8; ++i) {
                    asm("v_cvt_pk_bf16_f32 %0, %1, %2" : "=v"(pk0[i]) : "v"(p0[2 * i]), "v"(p0[2 * i + 1]));
                    asm("v_cvt_pk_bf16_f32 %0, %1, %2" : "=v"(pk1[i]) : "v"(p1[2 * i]), "v"(p1[2 * i + 1]));
                }
                uint4 bfr[4];
#pragma unroll
                for (int sg = 0; sg < 2; ++sg) {
                    unsigned int x0 = pk0[4 * sg], y0 = pk0[4 * sg + 2];
                    asm volatile("v_permlane32_swap_b32 %0, %1" : "+v"(x0), "+v"(y0));
                    unsigned int x1 = pk0[4 * sg + 1], y1 = pk0[4 * sg + 3];
                    asm volatile("v_permlane32_swap_b32 %0, %1" : "+v"(x1), "+v"(y1));
                    bfr[sg] = make_uint4(x0, x1, y0, y1);
                    unsigned int x2 = pk1[4 * sg], y2 = pk1[4 * sg + 2];
                    asm volatile("v_permlane32_swap_b32 %0, %1" : "+v"(x2), "+v"(y2));
                    unsigned int x3 = pk1[4 * sg + 1], y3 = pk1[4 * sg + 3];
                    asm volatile("v_permlane32_swap_b32 %0, %1" : "+v"(x3), "+v"(y3));
                    bfr[2 + sg] = make_uint4(x2, x3, y2, y3);
                }
                __builtin_amdgcn_s_setprio(1);
#pragma unroll
                for (int ss = 0; ss < 4; ++ss) {
                    short8 pb = __builtin_bit_cast(short8, bfr[ss]);
                    int vc = (((2 * ss + hb) ^ xh) << 3);
#pragma unroll
                    for (int dt = 0; dt < 4; ++dt) {
                        short8 vf = *(const short8*)&Vs[cur][dt * 32 + ql][vc];
                        o[dt] = __builtin_amdgcn_mfma_f32_32x32x16_bf16(vf, pb, o[dt], 0, 0, 0);
                    }
                }
                __builtin_amdgcn_s_setprio(0);
            }
            if (tt + 1 < cnt) writeV(cur ^ 1);
            __syncthreads();
        }

        l_r += __shfl_xor(l_r, 32);
        if (direct) {
            float inv_l = 1.f / l_r;
            unsigned int* ep = (unsigned int*)smem + wave * 2176;
#pragma unroll
            for (int dt = 0; dt < 4; ++dt)
#pragma unroll
                for (int r = 0; r < 16; r += 2) {
                    float a = o[dt][r] * inv_l, c2 = o[dt][r + 1] * inv_l;
                    unsigned int pkv;
                    asm("v_cvt_pk_bf16_f32 %0, %1, %2" : "=v"(pkv) : "v"(a), "v"(c2));
                    ep[ql * 68 + dt * 16 + ((r & 3) >> 1) + 4 * (r >> 2) + 2 * hb] = pkv;
                }
#pragma unroll
            for (int it = 0; it < 8; ++it) {
                int qr = lane >> 1, ch = (lane & 1) * 8 + it;
                uint4 w = *(uint4*)&ep[qr * 68 + ch * 4];
                *(uint4*)(attn_out + (size_t)(kvB + q0w + qr) * 2048 + h * 128 + ch * 8) = w;
            }
        } else {
            float* sW = (float*)smem + wg * 4224;
            const size_t pb2 = ((size_t)pairIdx * 2 + side);
#pragma unroll
            for (int pass = 0; pass < 2; ++pass) {
                if (pass == 1) __syncthreads();
                if (hsel == pass) {
#pragma unroll
                    for (int dt = 0; dt < 4; ++dt)
#pragma unroll
                        for (int r = 0; r < 16; ++r)
                            sW[ql * 132 + dt * 32 + (r & 3) + 8 * (r >> 2) + 4 * hb] = o[dt][r];
                    int q = lane >> 1, half = lane & 1;
                    const float* src = sW + q * 132 + half * 64;
                    unsigned int* dst = (unsigned int*)(partOb + pb2 * 16384 + ((size_t)(wg * 32 + q)) * 128 + half * 64);
#pragma unroll
                    for (int j = 0; j < 64; j += 4) {
                        float4 f = *(const float4*)(src + j);
                        unsigned int d0, d1;
                        asm("v_cvt_pk_bf16_f32 %0, %1, %2" : "=v"(d0) : "v"(f.x), "v"(f.y));
                        asm("v_cvt_pk_bf16_f32 %0, %1, %2" : "=v"(d1) : "v"(f.z), "v"(f.w));
                        *(uint2*)(dst + (j >> 1)) = make_uint2(d0, d1);
                    }
                    if (hb == 0) {
                        partL[pb2 * 128 + wg * 32 + ql] = l_r;
                        partM[pb2 * 128 + wg * 32 + ql] = m_raw;
                    }
                }
            }
        }
    };

    if (roleA) {
        run(qb * 128, 0, 2 * qb + 2, true, 0);
        run(hiqb * 128, 0, xsp, false, 0);
    } else {
        run(hiqb * 128, xsp, 17, false, 1);
    }
}

// merge the two partials of each hi q-tile (bf16 partO)
__global__ __launch_bounds__(256) void merge_kernel(
    const unsigned short* __restrict__ partOb, const float* __restrict__ partL,
    const float* __restrict__ partM, unsigned short* __restrict__ attn_out) {
    __shared__ float sA[128], sB[128], sI[128];
    const int p = blockIdx.x, tid = threadIdx.x;
    const int bh = p >> 3, qb = p & 7;
    const int b = bh >> 4, h = bh & 15;
    const int q0 = (15 - qb) * 128;
    const float sc2 = 0.12751744f;
    if (tid < 128) {
        float mA = partM[(size_t)(p * 2) * 128 + tid];
        float mB = partM[(size_t)(p * 2 + 1) * 128 + tid];
        float mM = fmaxf(mA, mB);
        float aA = exp2f((mA - mM) * sc2), aB = exp2f((mB - mM) * sc2);
        float lT = aA * partL[(size_t)(p * 2) * 128 + tid] + aB * partL[(size_t)(p * 2 + 1) * 128 + tid];
        sA[tid] = aA; sB[tid] = aB; sI[tid] = 1.f / lT;
    }
    __syncthreads();
    const int q = tid >> 1, half = tid & 1;
    const float aA = sA[q], aB = sB[q], inv = sI[q];
    const unsigned short* oA = partOb + (size_t)(p * 2) * 16384 + q * 128 + half * 64;
    const unsigned short* oB = partOb + (size_t)(p * 2 + 1) * 16384 + q * 128 + half * 64;
    unsigned short* dst = attn_out + (size_t)(b * SS + q0 + q) * 2048 + h * 128 + half * 64;
#pragma unroll
    for (int j = 0; j < 64; j += 4) {
        ushort4 ua = *(const ushort4*)(oA + j);
        ushort4 ub = *(const ushort4*)(oB + j);
        ushort4 u;
        u.x = f2bf((aA * bf2f(ua.x) + aB * bf2f(ub.x)) * inv);
        u.y = f2bf((aA * bf2f(ua.y) + aB * bf2f(ub.y)) * inv);
        u.z = f2bf((aA * bf2f(ua.z) + aB * bf2f(ub.z)) * inv);
        u.w = f2bf((aA * bf2f(ua.w) + aB * bf2f(ub.w)) * inv);
        *(ushort4*)(dst + j) = u;
    }
}

// ---------------- launcher ----------------

extern "C" void kernel_launch(void* const* d_in, const int* in_sizes, int n_in,
                              void* d_out, int out_size, void* d_ws, size_t ws_size,
                              hipStream_t stream) {
    const float* x     = (const float*)d_in[0];
    const float* W_dkv = (const float*)d_in[1];
    const float* W_dq  = (const float*)d_in[2];
    const float* W_kr  = (const float*)d_in[3];
    const float* W_qc  = (const float*)d_in[4];
    const float* W_qr  = (const float*)d_in[5];
    const float* W_uk  = (const float*)d_in[6];
    const float* W_uv  = (const float*)d_in[7];
    const float* W_o   = (const float*)d_in[8];
    float* out = (float*)d_out;

    size_t off = 0;
    auto alloc = [&](size_t bytes) {
        void* p = (char*)d_ws + off;
        off = (off + bytes + 255) & ~(size_t)255;
        return p;
    };
    unsigned short* WcatT = (unsigned short*)alloc((size_t)320 * 2048 * 2);
    unsigned short* Wq2T  = (unsigned short*)alloc((size_t)3072 * 128 * 2);
    unsigned short* WqcB  = (unsigned short*)alloc((size_t)16 * 128 * 64 * 2);
    unsigned short* WukB  = (unsigned short*)alloc((size_t)16 * 128 * 64 * 2);
    unsigned short* WuvB  = (unsigned short*)alloc((size_t)16 * 128 * 128 * 2);
    unsigned short* WoT   = (unsigned short*)alloc((size_t)2048 * 2048 * 2);
    unsigned short* WeffT = (unsigned short*)alloc((size_t)2048 * 2048 * 2);
    unsigned short* g1    = (unsigned short*)alloc((size_t)NTOK * 320 * 2);
    unsigned short* q_all = (unsigned short*)alloc((size_t)NTOK * QSTR * 2);
    unsigned short* ckv_t = (unsigned short*)alloc((size_t)2 * 128 * 2048 * 2);
    unsigned short* attn  = (unsigned short*)alloc((size_t)NTOK * 2048 * 2);
    float2* rope_tab      = (float2*)alloc((size_t)SS * 32 * sizeof(float2));
    unsigned short* partOb= (unsigned short*)alloc((size_t)256 * 2 * 16384 * 2);
    float* partL          = (float*)alloc((size_t)256 * 2 * 128 * 4);
    float* partM          = (float*)alloc((size_t)256 * 2 * 128 * 4);

    // 1: layouts + bf16 copies + rope table
    prep_kernel<<<6400, 256, 0, stream>>>(W_dkv, W_dq, W_kr, W_qc, W_qr, W_uk, W_uv, W_o,
                                          WcatT, Wq2T, WqcB, WukB, WuvB, WoT, rope_tab);
    // 2: absorbed-weight precomputes (wqk + weff fused)
    weights2_kernel<<<16 + 256, 256, 0, stream>>>(WqcB, WukB, Wq2T, WoT, WuvB, WeffT);
    // 3: latent GEMM (f32 A, conversion folded)
    gemm_lat_kernel<<<dim3(5, 32), 256, 0, stream>>>(x, WcatT, g1);
    // 4: c_kv transpose + k-rope (fused, both g1-dependent)
    ckvt_ropek_kernel<<<128 + 512, 256, 0, stream>>>(g1, ckv_t, rope_tab);
    // 5: absorbed q projection with fused q-rope epilogue
    gemm_q_kernel<<<dim3(24, 32), 256, 0, stream>>>(g1 + 128, Wq2T, q_all, rope_tab);
    // 6: attention (2 heads/block, split-pair balanced) + merge
    mla_attn_kernel<<<256, 512, 0, stream>>>(q_all, g1, ckv_t, attn, partOb, partL, partM);
    merge_kernel<<<256, 256, 0, stream>>>(partOb, partL, partM, attn);
    // 7: output projection with W_eff -> fp32 (deep-pipelined)
    gemm_out_kernel<<<dim3(8, 32), 512, 0, stream>>>(attn, WeffT, out);
}

// Round 13
// 225.770 us; speedup vs baseline: 1.0079x; 1.0079x over previous
//
#include <hip/hip_runtime.h>
#include <hip/hip_bf16.h>

typedef __attribute__((ext_vector_type(8))) short short8;
typedef __attribute__((ext_vector_type(4))) float f32x4;
typedef __attribute__((ext_vector_type(16))) float f32x16;

#define N_EMBED 2048
#define N_HEAD 16
#define BB 2
#define SS 2048
#define NTOK (BB*SS)          // 4096
#define HD2 192               // absorbed head dim: 128 latent + 64 rope
#define QSTR 3072             // q_all row stride = 16*192

__device__ __forceinline__ unsigned short f2bf(float f) {
    unsigned int b = __builtin_bit_cast(unsigned int, f);
    b += 0x7fffu + ((b >> 16) & 1u);
    return (unsigned short)(b >> 16);
}
__device__ __forceinline__ float bf2f(unsigned short u) {
    unsigned int b = ((unsigned int)u) << 16;
    return __builtin_bit_cast(float, b);
}

#define GLOAD_LDS16(gsrc, ldst) __builtin_amdgcn_global_load_lds( \
    (const __attribute__((address_space(1))) void*)(gsrc), \
    (__attribute__((address_space(3))) void*)(ldst), 16, 0, 0)

#define ROPE_COEF (-0.28782313662425575f)  // -ln(10000)/32

// ---------------- prep: layouts + bf16 copies + rope table ----------------
__global__ __launch_bounds__(256) void prep_kernel(
    const float* __restrict__ Wdkv, const float* __restrict__ Wdq, const float* __restrict__ Wkr,
    const float* __restrict__ Wqc, const float* __restrict__ Wqr,
    const float* __restrict__ Wuk, const float* __restrict__ Wuv, const float* __restrict__ Wo,
    unsigned short* __restrict__ WcatT, unsigned short* __restrict__ Wq2T,
    unsigned short* __restrict__ WqcB, unsigned short* __restrict__ WukB,
    unsigned short* __restrict__ WuvB, unsigned short* __restrict__ WoT,
    float2* __restrict__ rope_tab) {
    __shared__ float tile[64][65];
    const int bid = blockIdx.x, tid = threadIdx.x;
    if (bid < 2560) {                       // WcatT [320][2048]
        int i = bid * 256 + tid;
        int n = i >> 11, k = i & 2047;
        float v;
        if (n < 128)      v = Wdkv[k * 128 + n];
        else if (n < 256) v = Wdq[k * 128 + (n - 128)];
        else              v = Wkr[k * 64 + (n - 256)];
        WcatT[i] = f2bf(v);
    } else if (bid < 3072) {                // Wq2T rope rows: [h][64 jr][128 k]
        int i = (bid - 2560) * 256 + tid;
        int h = i >> 13, jr = (i >> 7) & 63, k = i & 127;
        Wq2T[((size_t)(h * HD2 + 128 + jr)) * 128 + k] = f2bf(Wqr[(h * 128 + k) * 64 + jr]);
    } else if (bid < 3584) {                // WqcB plain copy [16][128][64]
        int i = (bid - 3072) * 256 + tid;
        WqcB[i] = f2bf(Wqc[i]);
    } else if (bid < 4096) {                // WukB plain copy
        int i = (bid - 3584) * 256 + tid;
        WukB[i] = f2bf(Wuk[i]);
    } else if (bid < 5120) {                // WuvB plain copy [16][128][128]
        int i = (bid - 4096) * 256 + tid;
        WuvB[i] = f2bf(Wuv[i]);
    } else if (bid < 6144) {                // WoT [2048][2048] tiled transpose
        int tb = bid - 5120;
        const int k0 = (tb & 31) * 64, n0 = (tb >> 5) * 64;
        const int tr = tid >> 4, tc = (tid & 15) * 4;
#pragma unroll
        for (int it = 0; it < 4; ++it) {
            int r = it * 16 + tr;
            float4 v = *(const float4*)(Wo + (size_t)(k0 + r) * 2048 + n0 + tc);
            tile[r][tc] = v.x; tile[r][tc + 1] = v.y; tile[r][tc + 2] = v.z; tile[r][tc + 3] = v.w;
        }
        __syncthreads();
#pragma unroll
        for (int it = 0; it < 4; ++it) {
            int r = it * 16 + tr;
            ushort4 o;
            o.x = f2bf(tile[tc][r]); o.y = f2bf(tile[tc + 1][r]);
            o.z = f2bf(tile[tc + 2][r]); o.w = f2bf(tile[tc + 3][r]);
            *(ushort4*)(WoT + (size_t)(n0 + r) * 2048 + k0 + tc) = o;
        }
    } else {                                // rope table [SS][32]
        int i = (bid - 6144) * 256 + tid;
        int pos = i >> 5, j = i & 31;
        float freq = __expf(ROPE_COEF * (float)j);
        float a = (float)pos * freq;
        float s, c;
        __sincosf(a, &s, &c);
        rope_tab[i] = make_float2(c, s);
    }
}

// ---------------- fused weight GEMMs: wqk (bid 0-15) + weff (bid 16-271) ----------------
__global__ __launch_bounds__(256) void weights2_kernel(
    const unsigned short* __restrict__ WqcB,   // [16][128][64]
    const unsigned short* __restrict__ WukB,   // [16][128][64]
    unsigned short* __restrict__ Wq2T,         // [3072][128]
    const unsigned short* __restrict__ WoT,    // [2048][2048]
    const unsigned short* __restrict__ WuvB,   // [16][128][128]
    unsigned short* __restrict__ WeffT) {      // [2048][2048]
    __shared__ __align__(16) unsigned short As[2][128][32];
    __shared__ __align__(16) unsigned short Bs[2][128][32];
    const int bid = blockIdx.x;
    const int tid = threadIdx.x, wave = tid >> 6, lane = tid & 63;
    const int wr = wave >> 1, wc = wave & 1;
    const int lg = lane >> 4, lr = lane & 15;
    if (bid < 16) {
        const int h = bid;
        const unsigned short* A = WqcB + (size_t)h * 8192;
        const unsigned short* Bt = WukB + (size_t)h * 8192;
        f32x4 acc[4][4] = {};
#pragma unroll
        for (int kk = 0; kk < 2; ++kk) {
            short8 af[4], bfr[4];
#pragma unroll
            for (int i = 0; i < 4; i++) af[i] = *(const short8*)(A + (wr * 64 + i * 16 + lr) * 64 + kk * 32 + lg * 8);
#pragma unroll
            for (int j = 0; j < 4; j++) bfr[j] = *(const short8*)(Bt + (wc * 64 + j * 16 + lr) * 64 + kk * 32 + lg * 8);
#pragma unroll
            for (int i = 0; i < 4; i++)
#pragma unroll
                for (int j = 0; j < 4; j++)
                    acc[i][j] = __builtin_amdgcn_mfma_f32_16x16x32_bf16(af[i], bfr[j], acc[i][j], 0, 0, 0);
        }
#pragma unroll
        for (int i = 0; i < 4; i++)
#pragma unroll
            for (int j = 0; j < 4; j++)
#pragma unroll
                for (int r = 0; r < 4; r++) {
                    int row = wr * 64 + i * 16 + lg * 4 + r;   // k_in
                    int col = wc * 64 + j * 16 + lr;           // latent k'
                    Wq2T[((size_t)(h * HD2 + col)) * 128 + row] = f2bf(acc[i][j][r]);
                }
    } else {
        const int et = (bid - 16) & 15, h = (bid - 16) >> 4;
        const unsigned short* A = WoT + (size_t)et * 128 * 2048 + h * 128;
        const unsigned short* Bt = WuvB + (size_t)h * 16384;
        f32x4 acc[4][4] = {};
        auto stage = [&](int k0, int buf) {
#pragma unroll
            for (int it = 0; it < 2; ++it) {
                int e = (tid + it * 256) * 8;
                GLOAD_LDS16(A + (size_t)(e >> 5) * 2048 + k0 + (e & 31), &As[buf][0][0] + e);
            }
#pragma unroll
            for (int it = 0; it < 2; ++it) {
                int e = (tid + it * 256) * 8;
                GLOAD_LDS16(Bt + (size_t)(e >> 5) * 128 + k0 + (e & 31), &Bs[buf][0][0] + e);
            }
        };
        stage(0, 0);
        __syncthreads();
        for (int t = 0; t < 4; ++t) {
            const int cur = t & 1;
            if (t + 1 < 4) stage((t + 1) * 32, cur ^ 1);
            short8 af[4], bfr[4];
#pragma unroll
            for (int i = 0; i < 4; i++) af[i] = *(const short8*)&As[cur][wr * 64 + i * 16 + lr][lg * 8];
#pragma unroll
            for (int j = 0; j < 4; j++) bfr[j] = *(const short8*)&Bs[cur][wc * 64 + j * 16 + lr][lg * 8];
#pragma unroll
            for (int i = 0; i < 4; i++)
#pragma unroll
                for (int j = 0; j < 4; j++)
                    acc[i][j] = __builtin_amdgcn_mfma_f32_16x16x32_bf16(af[i], bfr[j], acc[i][j], 0, 0, 0);
            __syncthreads();
        }
#pragma unroll
        for (int i = 0; i < 4; i++)
#pragma unroll
            for (int j = 0; j < 4; j++)
#pragma unroll
                for (int r = 0; r < 4; r++) {
                    int row = et * 128 + wr * 64 + i * 16 + lg * 4 + r;   // e
                    int col = wc * 64 + j * 16 + lr;                      // dl
                    WeffT[(size_t)row * 2048 + h * 128 + col] = f2bf(acc[i][j][r]);
                }
    }
}

// ---------------- fused: ckv_t transpose (pre-swizzled) + rope_k ----------------
// ckv_t stored chunk-swizzled within each 64-col block: slot s of row d holds
// source chunk s^(d&7) -> attn stages V with linear global_load_lds (rule #21).
__global__ __launch_bounds__(256) void ckvt_ropek_kernel(
    unsigned short* __restrict__ g1, unsigned short* __restrict__ ckv_t,
    const float2* __restrict__ tab) {
    __shared__ unsigned short tile[64][65];
    const int bid = blockIdx.x, tid = threadIdx.x;
    if (bid < 128) {                        // ckv_t[b][dl][s] = g1[b*SS+s][dl], swizzled
        const int s0 = (bid & 31) * 64, d0 = ((bid >> 5) & 1) * 64, b = bid >> 6;
        const int tr = tid >> 4, tc = (tid & 15) * 4;
#pragma unroll
        for (int it = 0; it < 4; ++it) {
            int r = it * 16 + tr;
            *(ushort4*)&tile[r][tc] = *(const ushort4*)(g1 + (size_t)(b * SS + s0 + r) * 320 + d0 + tc);
        }
        __syncthreads();
#pragma unroll
        for (int it = 0; it < 4; ++it) {
            int r = it * 16 + tr;       // local d
            int d = d0 + r;
            ushort4 o;
            o.x = tile[tc][r]; o.y = tile[tc + 1][r]; o.z = tile[tc + 2][r]; o.w = tile[tc + 3][r];
            int chunk = tc >> 3;        // source chunk within this 64-block (tc%8 in {0,4})
            int col = ((chunk ^ (d & 7)) << 3) + (tc & 7);
            *(ushort4*)(ckv_t + ((size_t)b * 128 + d) * 2048 + s0 + col) = o;
        }
    } else {                                // rope_k: NTOK*32 elements
        int i = (bid - 128) * 256 + tid;
        int j = i & 31, row = i >> 5;
        int pos = row & (SS - 1);
        float2 cs = tab[(pos << 5) | j];
        unsigned short* p = g1 + (size_t)row * 320 + 256 + 2 * j;
        float x0 = bf2f(p[0]), x1 = bf2f(p[1]);
        p[0] = f2bf(x0 * cs.x - x1 * cs.y);
        p[1] = f2bf(x0 * cs.y + x1 * cs.x);
    }
}

// ---------------- q-projection with fused rope epilogue ----------------
__global__ __launch_bounds__(256) void gemm_q_kernel(
    const unsigned short* __restrict__ A,      // g1+128, lda 320
    const unsigned short* __restrict__ Bt,     // Wq2T [3072][128]
    unsigned short* __restrict__ C,            // q_all [NTOK][3072]
    const float2* __restrict__ tab) {
    constexpr int BM = 128, BN = 128, BK = 32;
    __shared__ __align__(16) unsigned short As[2][BM][BK];
    __shared__ __align__(16) unsigned short Bs[2][BN][BK];
    const int tid = threadIdx.x, wave = tid >> 6, lane = tid & 63;
    const int wr = wave >> 1, wc = wave & 1;
    const int lg = lane >> 4, lr = lane & 15;
    const int m0 = blockIdx.y * BM, n0 = blockIdx.x * BN;

    f32x4 acc[4][4] = {};
    auto stage = [&](int k0, int buf) {
#pragma unroll
        for (int it = 0; it < 2; ++it) {
            int e = (tid + it * 256) * 8;
            GLOAD_LDS16(A + (size_t)(m0 + (e >> 5)) * 320 + k0 + (e & 31), &As[buf][0][0] + e);
        }
#pragma unroll
        for (int it = 0; it < 2; ++it) {
            int e = (tid + it * 256) * 8;
            GLOAD_LDS16(Bt + (size_t)(n0 + (e >> 5)) * 128 + k0 + (e & 31), &Bs[buf][0][0] + e);
        }
    };
    stage(0, 0);
    __syncthreads();
    for (int t = 0; t < 4; ++t) {
        const int cur = t & 1;
        if (t + 1 < 4) stage((t + 1) * BK, cur ^ 1);
        short8 af[4], bfr[4];
#pragma unroll
        for (int i = 0; i < 4; i++) af[i] = *(const short8*)&As[cur][wr * 64 + i * 16 + lr][lg * 8];
#pragma unroll
        for (int j = 0; j < 4; j++) bfr[j] = *(const short8*)&Bs[cur][wc * 64 + j * 16 + lr][lg * 8];
#pragma unroll
        for (int i = 0; i < 4; i++)
#pragma unroll
            for (int j = 0; j < 4; j++)
                acc[i][j] = __builtin_amdgcn_mfma_f32_16x16x32_bf16(af[i], bfr[j], acc[i][j], 0, 0, 0);
        __syncthreads();
    }
#pragma unroll
    for (int i = 0; i < 4; i++)
#pragma unroll
        for (int j = 0; j < 4; j++) {
            const int colb = n0 + wc * 64 + j * 16;        // frag base (mult of 16)
            const int c6 = colb >> 6;
            const int h = (c6 * 43) >> 7;                  // colb/192 for colb<3072
            const int ch = colb - h * 192;                 // uniform per frag
#pragma unroll
            for (int r = 0; r < 4; r++) {
                int row = m0 + wr * 64 + i * 16 + lg * 4 + r;
                int col = colb + lr;
                float val = acc[i][j][r];
                if (ch >= 128) {                           // roped range (frag-uniform)
                    float partner = __shfl_xor(val, 1);
                    int jr = (ch + lr - 128) >> 1;         // pair index, same for lane pair
                    float2 cs = tab[((row & (SS - 1)) << 5) | jr];
                    val = (lr & 1) ? (partner * cs.y + val * cs.x)
                                   : (val * cs.x - partner * cs.y);
                }
                C[(size_t)row * QSTR + col] = f2bf(val);
            }
        }
}

// Latent GEMM with f32 A (conversion folded in)
__global__ __launch_bounds__(256) void gemm_lat_kernel(
    const float* __restrict__ A,               // [NTOK][2048] f32
    const unsigned short* __restrict__ Bt,     // WcatT [320][2048]
    unsigned short* __restrict__ C) {          // g1 [NTOK][320]
    constexpr int BM = 128, BN = 64, BK = 32, K = 2048;
    __shared__ __align__(16) unsigned short As[2][BM][BK];
    __shared__ __align__(16) unsigned short Bs[2][BN][BK];
    constexpr int WN = BN / 2, FM = 4, FN = WN / 16;
    const int tid = threadIdx.x, wave = tid >> 6, lane = tid & 63;
    const int wr = wave >> 1, wc = wave & 1;
    const int lg = lane >> 4, lr = lane & 15;
    const int m0 = blockIdx.y * BM, n0 = blockIdx.x * BN;

    f32x4 acc[FM][FN] = {};
    const int ar = (tid * 16) >> 5, ac = (tid * 16) & 31;

    float4 a4[4];
    auto loadA = [&](int k0) {
        const float* src = A + (size_t)(m0 + ar) * K + k0 + ac;
#pragma unroll
        for (int i = 0; i < 4; ++i) a4[i] = *(const float4*)(src + i * 4);
    };
    auto writeA = [&](int buf) {
        unsigned int pk[8];
        const float* f = (const float*)a4;
#pragma unroll
        for (int i = 0; i < 8; ++i)
            asm("v_cvt_pk_bf16_f32 %0, %1, %2" : "=v"(pk[i]) : "v"(f[2 * i]), "v"(f[2 * i + 1]));
        *(uint4*)&As[buf][ar][ac]     = make_uint4(pk[0], pk[1], pk[2], pk[3]);
        *(uint4*)&As[buf][ar][ac + 8] = make_uint4(pk[4], pk[5], pk[6], pk[7]);
    };
    auto stageB = [&](int k0, int buf) {
        int e = tid * 8;
        GLOAD_LDS16(Bt + (size_t)(n0 + (e >> 5)) * K + k0 + (e & 31), &Bs[buf][0][0] + e);
    };

    loadA(0); stageB(0, 0); writeA(0);
    __syncthreads();
    constexpr int nk = K / BK;
    for (int t = 0; t < nk; ++t) {
        const int cur = t & 1;
        if (t + 1 < nk) { loadA((t + 1) * BK); stageB((t + 1) * BK, cur ^ 1); }
        short8 af[FM], bfr[FN];
#pragma unroll
        for (int i = 0; i < FM; i++) af[i] = *(const short8*)&As[cur][wr * 64 + i * 16 + lr][lg * 8];
#pragma unroll
        for (int j = 0; j < FN; j++) bfr[j] = *(const short8*)&Bs[cur][wc * WN + j * 16 + lr][lg * 8];
#pragma unroll
        for (int i = 0; i < FM; i++)
#pragma unroll
            for (int j = 0; j < FN; j++)
                acc[i][j] = __builtin_amdgcn_mfma_f32_16x16x32_bf16(af[i], bfr[j], acc[i][j], 0, 0, 0);
        if (t + 1 < nk) writeA(cur ^ 1);
        __syncthreads();
    }
#pragma unroll
    for (int i = 0; i < FM; i++)
#pragma unroll
        for (int j = 0; j < FN; j++)
#pragma unroll
            for (int r = 0; r < 4; r++) {
                int row = m0 + wr * 64 + i * 16 + lg * 4 + r;
                int col = n0 + wc * WN + j * 16 + lr;
                C[(size_t)row * 320 + col] = f2bf(acc[i][j][r]);
            }
}

// ---------------- out-proj: 128x256 deep-pipelined GEMM (T2+T3+T4+T5) ----------------
__global__ __launch_bounds__(512, 2) void gemm_out_kernel(
    const unsigned short* __restrict__ Ag,     // attn [4096][2048]
    const unsigned short* __restrict__ Bg,     // WeffT [2048][2048]
    float* __restrict__ C) {
    __shared__ __align__(16) unsigned short As[3][128][64];
    __shared__ __align__(16) unsigned short Bs[3][256][64];
    const int tid = threadIdx.x, wave = tid >> 6, lane = tid & 63;
    const int wr = wave >> 2, wc = wave & 3;
    const int lg = lane >> 4, lr = lane & 15;
    int id = blockIdx.y * gridDim.x + blockIdx.x;      // grid (8, 32) = 256
    int swz = (id & 7) * 32 + (id >> 3);               // bijective XCD grouping
    const int n0 = (swz & 7) * 256;
    const int m0 = (swz >> 3) * 128;

    f32x4 acc[4][4] = {};

    auto STAGE = [&](int kt, int buf) {
        const int k0 = kt * 64;
#pragma unroll
        for (int it = 0; it < 2; ++it) {               // A: 128 rows x 8 chunks
            int cid = tid + it * 512;
            int row = cid >> 3, slot = cid & 7;
            int csrc = slot ^ (row & 7);
            GLOAD_LDS16(Ag + (size_t)(m0 + row) * 2048 + k0 + csrc * 8, &As[buf][0][0] + cid * 8);
        }
#pragma unroll
        for (int it = 0; it < 4; ++it) {               // B: 256 rows x 8 chunks
            int cid = tid + it * 512;
            int row = cid >> 3, slot = cid & 7;
            int csrc = slot ^ (row & 7);
            GLOAD_LDS16(Bg + (size_t)(n0 + row) * 2048 + k0 + csrc * 8, &Bs[buf][0][0] + cid * 8);
        }
    };
    auto compute = [&](int buf) {
#pragma unroll
        for (int ks = 0; ks < 2; ++ks) {
            const int ca = ((ks * 4 + lg) ^ (lr & 7)) * 8;   // swizzled read chunk
            short8 af[4], bfr[4];
#pragma unroll
            for (int i = 0; i < 4; i++) af[i] = *(const short8*)&As[buf][wr * 64 + i * 16 + lr][ca];
#pragma unroll
            for (int j = 0; j < 4; j++) bfr[j] = *(const short8*)&Bs[buf][wc * 64 + j * 16 + lr][ca];
            __builtin_amdgcn_s_setprio(1);
#pragma unroll
            for (int i = 0; i < 4; i++)
#pragma unroll
                for (int j = 0; j < 4; j++)
                    acc[i][j] = __builtin_amdgcn_mfma_f32_16x16x32_bf16(af[i], bfr[j], acc[i][j], 0, 0, 0);
            __builtin_amdgcn_s_setprio(0);
        }
    };

    STAGE(0, 0); STAGE(1, 1); STAGE(2, 2);             // 18 loads in flight
    for (int t = 0; t < 30; ++t) {
        asm volatile("s_waitcnt vmcnt(12)" ::: "memory");
        __builtin_amdgcn_s_barrier();
        asm volatile("" ::: "memory");
        compute(t % 3);
        asm volatile("" ::: "memory");
        __builtin_amdgcn_s_barrier();
        if (t < 29) STAGE(t + 3, t % 3);
    }
    asm volatile("s_waitcnt vmcnt(6)" ::: "memory");
    __builtin_amdgcn_s_barrier();
    asm volatile("" ::: "memory");
    compute(0);
    asm volatile("" ::: "memory");
    __builtin_amdgcn_s_barrier();
    asm volatile("s_waitcnt vmcnt(0)" ::: "memory");
    __builtin_amdgcn_s_barrier();
    asm volatile("" ::: "memory");
    compute(1);

#pragma unroll
    for (int i = 0; i < 4; i++)
#pragma unroll
        for (int j = 0; j < 4; j++)
#pragma unroll
            for (int r = 0; r < 4; r++) {
                int row = m0 + wr * 64 + i * 16 + lg * 4 + r;
                int col = n0 + wc * 64 + j * 16 + lr;
                C[(size_t)row * 2048 + col] = acc[i][j][r];
            }
}

// ---------------- flash attention v10: 3-buffer counted-vmcnt pipeline ----------------
// 256 blocks x 512 threads, 2 heads/block, split-pair balance (as v9) PLUS:
// all K/V staging via global_load_lds (V source pre-swizzled in ckv_t), 3 LDS
// buffers (120KB), depth-2 prefetch, counted vmcnt (5 vmem ops/thread/stage,
// never drained to 0 in the loop), raw s_barrier.
__global__ __launch_bounds__(512) void mla_attn_kernel(
    const unsigned short* __restrict__ q_all,   // [NTOK][3072]: per head [qtil(128)|qrope(64)]
    const unsigned short* __restrict__ g1,      // [NTOK][320]: ckv 0..127, roped k_r 256..319
    const unsigned short* __restrict__ ckv_t,   // [2][128][2048] chunk-swizzled
    unsigned short* __restrict__ attn_out,      // [NTOK][2048] (o_lat)
    unsigned short* __restrict__ partOb,        // [256 pair][2 side][128 q][128 d] bf16
    float* __restrict__ partL,
    float* __restrict__ partM) {
    __shared__ __align__(16) char smem[122880];
    auto Ks = (unsigned short (*)[64][192])smem;             // [3][64][192], chunk-swizzled
    auto Vs = (unsigned short (*)[128][64])(smem + 73728);   // [3][128][64], chunk-swizzled

    const int id = blockIdx.x;
    const int xcd = id & 7, loc = id >> 3;
    const int hp = 2 * xcd + (loc >> 4);        // head-pair 0..15
    const int s2 = loc & 15;
    const bool roleA = s2 < 8;
    const int qb = roleA ? s2 : s2 - 8;
    const int hiqb = 15 - qb, xsp = 15 - 2 * qb;
    const int b = hp >> 3;
    const int tid = threadIdx.x, wave = tid >> 6, lane = tid & 63;
    const int wg = wave & 3, hsel = wave >> 2;
    const int h = (hp & 7) * 2 + hsel;
    const int bh = b * 16 + h;
    const int pairIdx = bh * 8 + qb;
    const int ql = lane & 31, hb = lane >> 5;
    const int kvB = b * SS;
    const float sc2 = 0.12751744f;   // (1/sqrt(128)) * log2(e)
    const int xh = ql & 7;

    auto stageK = [&](int t, int bufi) {       // 3 gload_lds / thread
#pragma unroll
        for (int it = 0; it < 3; ++it) {
            int cid = tid + it * 512;
            int r = cid / 24, s = cid - r * 24;
            int c = s ^ (r & 7);
            int col = (c < 16) ? c * 8 : 256 + (c - 16) * 8;
            GLOAD_LDS16(g1 + (size_t)(kvB + t * 64 + r) * 320 + col,
                        &Ks[bufi][0][0] + cid * 8);
        }
    };
    auto stageV = [&](int t, int bufi) {       // 2 gload_lds / thread (src pre-swizzled)
#pragma unroll
        for (int it = 0; it < 2; ++it) {
            int e = tid * 8 + it * 4096;
            GLOAD_LDS16(ckv_t + ((size_t)b * 128 + (e >> 6)) * 2048 + t * 64 + (e & 63),
                        &Vs[bufi][0][0] + e);
        }
    };

    auto run = [&](int q0, int t0, int cnt, bool direct, int side) {
        __syncthreads();                       // fence prior smem use (drains prior vmem too)
        const int q0w = q0 + wg * 32;
        const int qg = q0w + ql;

        short8 qf[12];
        {
            const unsigned short* qp = q_all + (size_t)(kvB + qg) * QSTR + h * HD2 + hb * 8;
#pragma unroll
            for (int ss = 0; ss < 12; ++ss) qf[ss] = *(const short8*)(qp + 16 * ss);
        }
        f32x16 o[4] = {};
        float m_raw = -3e38f, mb = 0.f, l_r = 0.f;

        stageK(t0, 0); stageV(t0, 0);
        if (cnt > 1) { stageK(t0 + 1, 1); stageV(t0 + 1, 1); }
        if (cnt > 2) { stageK(t0 + 2, 2); stageV(t0 + 2, 2); }

        for (int tt = 0; tt < cnt; ++tt) {
            const int t = t0 + tt;
            const int cur = tt % 3;
            int ahead = cnt - tt - 1; if (ahead > 2) ahead = 2;
            if (ahead == 2)      asm volatile("s_waitcnt vmcnt(10)" ::: "memory");
            else if (ahead == 1) asm volatile("s_waitcnt vmcnt(5)" ::: "memory");
            else                 asm volatile("s_waitcnt vmcnt(0)" ::: "memory");
            __builtin_amdgcn_s_barrier();       // tile tt landed for ALL waves
            asm volatile("" ::: "memory");
            {
                f32x16 p0 = {}, p1 = {};
                __builtin_amdgcn_s_setprio(1);
#pragma unroll
                for (int ss = 0; ss < 12; ++ss) {
                    int pc = (((2 * ss + hb) ^ xh) << 3);
                    short8 k0 = *(const short8*)&Ks[cur][ql][pc];
                    short8 k1 = *(const short8*)&Ks[cur][32 + ql][pc];
                    p0 = __builtin_amdgcn_mfma_f32_32x32x16_bf16(k0, qf[ss], p0, 0, 0, 0);
                    p1 = __builtin_amdgcn_mfma_f32_32x32x16_bf16(k1, qf[ss], p1, 0, 0, 0);
                }
                __builtin_amdgcn_s_setprio(0);
                const int kv0 = t * 64;
                if (kv0 + 63 > q0w) {
#pragma unroll
                    for (int r = 0; r < 16; ++r) {
                        int kvg = kv0 + (r & 3) + 8 * (r >> 2) + 4 * hb;
                        if (kvg > qg) p0[r] = -3e38f;
                        if (kvg + 32 > qg) p1[r] = -3e38f;
                    }
                }
                float pm = -3e38f;
#pragma unroll
                for (int r = 0; r < 16; ++r) pm = fmaxf(pm, fmaxf(p0[r], p1[r]));
                pm = fmaxf(pm, __shfl_xor(pm, 32));
                if (__any(pm > m_raw + 64.f)) {   // defer-max (T13)
                    float mn = fmaxf(m_raw, pm);
                    float alpha = exp2f((m_raw - mn) * sc2);
                    m_raw = mn; mb = mn * sc2;
                    l_r *= alpha;
#pragma unroll
                    for (int dt = 0; dt < 4; ++dt)
#pragma unroll
                        for (int r = 0; r < 16; ++r) o[dt][r] *= alpha;
                }
                float ps = 0.f;
#pragma unroll
                for (int r = 0; r < 16; ++r) {
                    p0[r] = exp2f(__builtin_fmaf(p0[r], sc2, -mb));
                    p1[r] = exp2f(__builtin_fmaf(p1[r], sc2, -mb));
                    ps += p0[r] + p1[r];
                }
                l_r += ps;
                unsigned int pk0[8], pk1[8];
#pragma unroll
                for (int i = 0; i < 8; ++i) {
                    asm("v_cvt_pk_bf16_f32 %0, %1, %2" : "=v"(pk0[i]) : "v"(p0[2 * i]), "v"(p0[2 * i + 1]));
                    asm("v_cvt_pk_bf16_f32 %0, %1, %2" : "=v"(pk1[i]) : "v"(p1[2 * i]), "v"(p1[2 * i + 1]));
                }
                uint4 bfr[4];
#pragma unroll
                for (int sg = 0; sg < 2; ++sg) {
                    unsigned int x0 = pk0[4 * sg], y0 = pk0[4 * sg + 2];
                    asm volatile("v_permlane32_swap_b32 %0, %1" : "+v"(x0), "+v"(y0));
                    unsigned int x1 = pk0[4 * sg + 1], y1 = pk0[4 * sg + 3];
                    asm volatile("v_permlane32_swap_b32 %0, %1" : "+v"(x1), "+v"(y1));
                    bfr[sg] = make_uint4(x0, x1, y0, y1);
                    unsigned int x2 = pk1[4 * sg], y2 = pk1[4 * sg + 2];
                    asm volatile("v_permlane32_swap_b32 %0, %1" : "+v"(x2), "+v"(y2));
                    unsigned int x3 = pk1[4 * sg + 1], y3 = pk1[4 * sg + 3];
                    asm volatile("v_permlane32_swap_b32 %0, %1" : "+v"(x3), "+v"(y3));
                    bfr[2 + sg] = make_uint4(x2, x3, y2, y3);
                }
                __builtin_amdgcn_s_setprio(1);
#pragma unroll
                for (int ss = 0; ss < 4; ++ss) {
                    short8 pb = __builtin_bit_cast(short8, bfr[ss]);
                    int vc = (((2 * ss + hb) ^ xh) << 3);
#pragma unroll
                    for (int dt = 0; dt < 4; ++dt) {
                        short8 vf = *(const short8*)&Vs[cur][dt * 32 + ql][vc];
                        o[dt] = __builtin_amdgcn_mfma_f32_32x32x16_bf16(vf, pb, o[dt], 0, 0, 0);
                    }
                }
                __builtin_amdgcn_s_setprio(0);
            }
            asm volatile("" ::: "memory");
            __builtin_amdgcn_s_barrier();       // all waves done reading buf cur
            if (tt + 3 < cnt) { stageK(t + 3, cur); stageV(t + 3, cur); }
        }

        l_r += __shfl_xor(l_r, 32);
        if (direct) {
            float inv_l = 1.f / l_r;
            unsigned int* ep = (unsigned int*)smem + wave * 2176;
#pragma unroll
            for (int dt = 0; dt < 4; ++dt)
#pragma unroll
                for (int r = 0; r < 16; r += 2) {
                    float a = o[dt][r] * inv_l, c2 = o[dt][r + 1] * inv_l;
                    unsigned int pkv;
                    asm("v_cvt_pk_bf16_f32 %0, %1, %2" : "=v"(pkv) : "v"(a), "v"(c2));
                    ep[ql * 68 + dt * 16 + ((r & 3) >> 1) + 4 * (r >> 2) + 2 * hb] = pkv;
                }
#pragma unroll
            for (int it = 0; it < 8; ++it) {
                int qr = lane >> 1, ch = (lane & 1) * 8 + it;
                uint4 w = *(uint4*)&ep[qr * 68 + ch * 4];
                *(uint4*)(attn_out + (size_t)(kvB + q0w + qr) * 2048 + h * 128 + ch * 8) = w;
            }
        } else {
            float* sW = (float*)smem + wg * 4224;
            const size_t pb2 = ((size_t)pairIdx * 2 + side);
#pragma unroll
            for (int pass = 0; pass < 2; ++pass) {
                if (pass == 1) __syncthreads();
                if (hsel == pass) {
#pragma unroll
                    for (int dt = 0; dt < 4; ++dt)
#pragma unroll
                        for (int r = 0; r < 16; ++r)
                            sW[ql * 132 + dt * 32 + (r & 3) + 8 * (r >> 2) + 4 * hb] = o[dt][r];
                    int q = lane >> 1, half = lane & 1;
                    const float* src = sW + q * 132 + half * 64;
                    unsigned int* dst = (unsigned int*)(partOb + pb2 * 16384 + ((size_t)(wg * 32 + q)) * 128 + half * 64);
#pragma unroll
                    for (int j = 0; j < 64; j += 4) {
                        float4 f = *(const float4*)(src + j);
                        unsigned int d0, d1;
                        asm("v_cvt_pk_bf16_f32 %0, %1, %2" : "=v"(d0) : "v"(f.x), "v"(f.y));
                        asm("v_cvt_pk_bf16_f32 %0, %1, %2" : "=v"(d1) : "v"(f.z), "v"(f.w));
                        *(uint2*)(dst + (j >> 1)) = make_uint2(d0, d1);
                    }
                    if (hb == 0) {
                        partL[pb2 * 128 + wg * 32 + ql] = l_r;
                        partM[pb2 * 128 + wg * 32 + ql] = m_raw;
                    }
                }
            }
        }
    };

    if (roleA) {
        run(qb * 128, 0, 2 * qb + 2, true, 0);
        run(hiqb * 128, 0, xsp, false, 0);
    } else {
        run(hiqb * 128, xsp, 17, false, 1);
    }
}

// merge the two partials of each hi q-tile (bf16 partO)
__global__ __launch_bounds__(256) void merge_kernel(
    const unsigned short* __restrict__ partOb, const float* __restrict__ partL,
    const float* __restrict__ partM, unsigned short* __restrict__ attn_out) {
    __shared__ float sA[128], sB[128], sI[128];
    const int p = blockIdx.x, tid = threadIdx.x;
    const int bh = p >> 3, qb = p & 7;
    const int b = bh >> 4, h = bh & 15;
    const int q0 = (15 - qb) * 128;
    const float sc2 = 0.12751744f;
    if (tid < 128) {
        float mA = partM[(size_t)(p * 2) * 128 + tid];
        float mB = partM[(size_t)(p * 2 + 1) * 128 + tid];
        float mM = fmaxf(mA, mB);
        float aA = exp2f((mA - mM) * sc2), aB = exp2f((mB - mM) * sc2);
        float lT = aA * partL[(size_t)(p * 2) * 128 + tid] + aB * partL[(size_t)(p * 2 + 1) * 128 + tid];
        sA[tid] = aA; sB[tid] = aB; sI[tid] = 1.f / lT;
    }
    __syncthreads();
    const int q = tid >> 1, half = tid & 1;
    const float aA = sA[q], aB = sB[q], inv = sI[q];
    const unsigned short* oA = partOb + (size_t)(p * 2) * 16384 + q * 128 + half * 64;
    const unsigned short* oB = partOb + (size_t)(p * 2 + 1) * 16384 + q * 128 + half * 64;
    unsigned short* dst = attn_out + (size_t)(b * SS + q0 + q) * 2048 + h * 128 + half * 64;
#pragma unroll
    for (int j = 0; j < 64; j += 4) {
        ushort4 ua = *(const ushort4*)(oA + j);
        ushort4 ub = *(const ushort4*)(oB + j);
        ushort4 u;
        u.x = f2bf((aA * bf2f(ua.x) + aB * bf2f(ub.x)) * inv);
        u.y = f2bf((aA * bf2f(ua.y) + aB * bf2f(ub.y)) * inv);
        u.z = f2bf((aA * bf2f(ua.z) + aB * bf2f(ub.z)) * inv);
        u.w = f2bf((aA * bf2f(ua.w) + aB * bf2f(ub.w)) * inv);
        *(ushort4*)(dst + j) = u;
    }
}

// ---------------- launcher ----------------

extern "C" void kernel_launch(void* const* d_in, const int* in_sizes, int n_in,
                              void* d_out, int out_size, void* d_ws, size_t ws_size,
                              hipStream_t stream) {
    const float* x     = (const float*)d_in[0];
    const float* W_dkv = (const float*)d_in[1];
    const float* W_dq  = (const float*)d_in[2];
    const float* W_kr  = (const float*)d_in[3];
    const float* W_qc  = (const float*)d_in[4];
    const float* W_qr  = (const float*)d_in[5];
    const float* W_uk  = (const float*)d_in[6];
    const float* W_uv  = (const float*)d_in[7];
    const float* W_o   = (const float*)d_in[8];
    float* out = (float*)d_out;

    size_t off = 0;
    auto alloc = [&](size_t bytes) {
        void* p = (char*)d_ws + off;
        off = (off + bytes + 255) & ~(size_t)255;
        return p;
    };
    unsigned short* WcatT = (unsigned short*)alloc((size_t)320 * 2048 * 2);
    unsigned short* Wq2T  = (unsigned short*)alloc((size_t)3072 * 128 * 2);
    unsigned short* WqcB  = (unsigned short*)alloc((size_t)16 * 128 * 64 * 2);
    unsigned short* WukB  = (unsigned short*)alloc((size_t)16 * 128 * 64 * 2);
    unsigned short* WuvB  = (unsigned short*)alloc((size_t)16 * 128 * 128 * 2);
    unsigned short* WoT   = (unsigned short*)alloc((size_t)2048 * 2048 * 2);
    unsigned short* WeffT = (unsigned short*)alloc((size_t)2048 * 2048 * 2);
    unsigned short* g1    = (unsigned short*)alloc((size_t)NTOK * 320 * 2);
    unsigned short* q_all = (unsigned short*)alloc((size_t)NTOK * QSTR * 2);
    unsigned short* ckv_t = (unsigned short*)alloc((size_t)2 * 128 * 2048 * 2);
    unsigned short* attn  = (unsigned short*)alloc((size_t)NTOK * 2048 * 2);
    float2* rope_tab      = (float2*)alloc((size_t)SS * 32 * sizeof(float2));
    unsigned short* partOb= (unsigned short*)alloc((size_t)256 * 2 * 16384 * 2);
    float* partL          = (float*)alloc((size_t)256 * 2 * 128 * 4);
    float* partM          = (float*)alloc((size_t)256 * 2 * 128 * 4);

    // 1: layouts + bf16 copies + rope table
    prep_kernel<<<6400, 256, 0, stream>>>(W_dkv, W_dq, W_kr, W_qc, W_qr, W_uk, W_uv, W_o,
                                          WcatT, Wq2T, WqcB, WukB, WuvB, WoT, rope_tab);
    // 2: absorbed-weight precomputes (wqk + weff fused)
    weights2_kernel<<<16 + 256, 256, 0, stream>>>(WqcB, WukB, Wq2T, WoT, WuvB, WeffT);
    // 3: latent GEMM (f32 A, conversion folded)
    gemm_lat_kernel<<<dim3(5, 32), 256, 0, stream>>>(x, WcatT, g1);
    // 4: c_kv transpose (pre-swizzled) + k-rope
    ckvt_ropek_kernel<<<128 + 512, 256, 0, stream>>>(g1, ckv_t, rope_tab);
    // 5: absorbed q projection with fused q-rope epilogue
    gemm_q_kernel<<<dim3(24, 32), 256, 0, stream>>>(g1 + 128, Wq2T, q_all, rope_tab);
    // 6: attention (3-buffer counted-vmcnt pipeline) + merge
    mla_attn_kernel<<<256, 512, 0, stream>>>(q_all, g1, ckv_t, attn, partOb, partL, partM);
    merge_kernel<<<256, 256, 0, stream>>>(partOb, partL, partM, attn);
    // 7: output projection with W_eff -> fp32 (deep-pipelined)
    gemm_out_kernel<<<dim3(8, 32), 512, 0, stream>>>(attn, WeffT, out);
}

// Round 14
// 199.346 us; speedup vs baseline: 1.1415x; 1.1326x over previous
//
#include <hip/hip_runtime.h>
#include <hip/hip_bf16.h>

typedef __attribute__((ext_vector_type(8))) short short8;
typedef __attribute__((ext_vector_type(4))) float f32x4;
typedef __attribute__((ext_vector_type(16))) float f32x16;

#define N_EMBED 2048
#define N_HEAD 16
#define BB 2
#define SS 2048
#define NTOK (BB*SS)          // 4096
#define HD2 192               // absorbed head dim: 128 latent + 64 rope
#define QSTR 3072             // q_all row stride = 16*192

__device__ __forceinline__ unsigned short f2bf(float f) {
    unsigned int b = __builtin_bit_cast(unsigned int, f);
    b += 0x7fffu + ((b >> 16) & 1u);
    return (unsigned short)(b >> 16);
}
__device__ __forceinline__ float bf2f(unsigned short u) {
    unsigned int b = ((unsigned int)u) << 16;
    return __builtin_bit_cast(float, b);
}

#define GLOAD_LDS16(gsrc, ldst) __builtin_amdgcn_global_load_lds( \
    (const __attribute__((address_space(1))) void*)(gsrc), \
    (__attribute__((address_space(3))) void*)(ldst), 16, 0, 0)

#define ROPE_COEF (-0.28782313662425575f)  // -ln(10000)/32

// ---------------- prep v2: all-coalesced layouts + rope table ----------------
// [0,160)    WcatT transpose (2048x320 f32 -> [320][2048] bf16), 64x64 LDS tiles
// [160,192)  Wq2T rope rows transpose (per-head 128x64)
// [192,320)  WqcB vec4 copy | [320,448) WukB | [448,704) WuvB
// [704,1728) WoT transpose | [1728,1984) rope table
__global__ __launch_bounds__(256) void prep_kernel(
    const float* __restrict__ Wdkv, const float* __restrict__ Wdq, const float* __restrict__ Wkr,
    const float* __restrict__ Wqc, const float* __restrict__ Wqr,
    const float* __restrict__ Wuk, const float* __restrict__ Wuv, const float* __restrict__ Wo,
    unsigned short* __restrict__ WcatT, unsigned short* __restrict__ Wq2T,
    unsigned short* __restrict__ WqcB, unsigned short* __restrict__ WukB,
    unsigned short* __restrict__ WuvB, unsigned short* __restrict__ WoT,
    float2* __restrict__ rope_tab) {
    __shared__ float tile[64][65];
    const int bid = blockIdx.x, tid = threadIdx.x;
    const int tr = tid >> 4, tc = (tid & 15) * 4;
    if (bid < 160) {                        // WcatT [320][2048] via tiled transpose
        const int k0 = (bid & 31) * 64, n0 = (bid >> 5) * 64;
        const float* W; int base, width;
        if (n0 < 128)      { W = Wdkv; base = 0;   width = 128; }
        else if (n0 < 256) { W = Wdq;  base = 128; width = 128; }
        else               { W = Wkr;  base = 256; width = 64; }
#pragma unroll
        for (int it = 0; it < 4; ++it) {
            int r = it * 16 + tr;
            float4 v = *(const float4*)(W + (size_t)(k0 + r) * width + (n0 - base) + tc);
            tile[r][tc] = v.x; tile[r][tc + 1] = v.y; tile[r][tc + 2] = v.z; tile[r][tc + 3] = v.w;
        }
        __syncthreads();
#pragma unroll
        for (int it = 0; it < 4; ++it) {
            int r = it * 16 + tr;           // n-local
            ushort4 o;
            o.x = f2bf(tile[tc][r]); o.y = f2bf(tile[tc + 1][r]);
            o.z = f2bf(tile[tc + 2][r]); o.w = f2bf(tile[tc + 3][r]);
            *(ushort4*)(WcatT + (size_t)(n0 + r) * 2048 + k0 + tc) = o;
        }
    } else if (bid < 192) {                 // Wq2T rope rows: transpose Wqr[h] (128k x 64jr)
        const int tb = bid - 160;
        const int h = tb >> 1, k0 = (tb & 1) * 64;
#pragma unroll
        for (int it = 0; it < 4; ++it) {
            int r = it * 16 + tr;           // k-local
            float4 v = *(const float4*)(Wqr + (size_t)(h * 128 + k0 + r) * 64 + tc);
            tile[r][tc] = v.x; tile[r][tc + 1] = v.y; tile[r][tc + 2] = v.z; tile[r][tc + 3] = v.w;
        }
        __syncthreads();
#pragma unroll
        for (int it = 0; it < 4; ++it) {
            int rr = it * 16 + tr;          // jr
            ushort4 o;
            o.x = f2bf(tile[tc][rr]); o.y = f2bf(tile[tc + 1][rr]);
            o.z = f2bf(tile[tc + 2][rr]); o.w = f2bf(tile[tc + 3][rr]);
            *(ushort4*)(Wq2T + (size_t)(h * HD2 + 128 + rr) * 128 + k0 + tc) = o;
        }
    } else if (bid < 320) {                 // WqcB copy [16][128][64]
        int i = (bid - 192) * 1024 + tid * 4;
        float4 v = *(const float4*)(Wqc + i);
        ushort4 o; o.x = f2bf(v.x); o.y = f2bf(v.y); o.z = f2bf(v.z); o.w = f2bf(v.w);
        *(ushort4*)(WqcB + i) = o;
    } else if (bid < 448) {                 // WukB copy
        int i = (bid - 320) * 1024 + tid * 4;
        float4 v = *(const float4*)(Wuk + i);
        ushort4 o; o.x = f2bf(v.x); o.y = f2bf(v.y); o.z = f2bf(v.z); o.w = f2bf(v.w);
        *(ushort4*)(WukB + i) = o;
    } else if (bid < 704) {                 // WuvB copy [16][128][128]
        int i = (bid - 448) * 1024 + tid * 4;
        float4 v = *(const float4*)(Wuv + i);
        ushort4 o; o.x = f2bf(v.x); o.y = f2bf(v.y); o.z = f2bf(v.z); o.w = f2bf(v.w);
        *(ushort4*)(WuvB + i) = o;
    } else if (bid < 1728) {                // WoT [2048][2048] tiled transpose
        int tb = bid - 704;
        const int k0 = (tb & 31) * 64, n0 = (tb >> 5) * 64;
#pragma unroll
        for (int it = 0; it < 4; ++it) {
            int r = it * 16 + tr;
            float4 v = *(const float4*)(Wo + (size_t)(k0 + r) * 2048 + n0 + tc);
            tile[r][tc] = v.x; tile[r][tc + 1] = v.y; tile[r][tc + 2] = v.z; tile[r][tc + 3] = v.w;
        }
        __syncthreads();
#pragma unroll
        for (int it = 0; it < 4; ++it) {
            int r = it * 16 + tr;
            ushort4 o;
            o.x = f2bf(tile[tc][r]); o.y = f2bf(tile[tc + 1][r]);
            o.z = f2bf(tile[tc + 2][r]); o.w = f2bf(tile[tc + 3][r]);
            *(ushort4*)(WoT + (size_t)(n0 + r) * 2048 + k0 + tc) = o;
        }
    } else {                                // rope table [SS][32]
        int i = (bid - 1728) * 256 + tid;
        int pos = i >> 5, j = i & 31;
        float freq = __expf(ROPE_COEF * (float)j);
        float a = (float)pos * freq;
        float s, c;
        __sincosf(a, &s, &c);
        rope_tab[i] = make_float2(c, s);
    }
}

// ---------------- fused weight GEMMs: wqk (bid 0-15) + weff (bid 16-271) ----------------
__global__ __launch_bounds__(256) void weights2_kernel(
    const unsigned short* __restrict__ WqcB,   // [16][128][64]
    const unsigned short* __restrict__ WukB,   // [16][128][64]
    unsigned short* __restrict__ Wq2T,         // [3072][128]
    const unsigned short* __restrict__ WoT,    // [2048][2048]
    const unsigned short* __restrict__ WuvB,   // [16][128][128]
    unsigned short* __restrict__ WeffT) {      // [2048][2048]
    __shared__ __align__(16) unsigned short As[2][128][32];
    __shared__ __align__(16) unsigned short Bs[2][128][32];
    const int bid = blockIdx.x;
    const int tid = threadIdx.x, wave = tid >> 6, lane = tid & 63;
    const int wr = wave >> 1, wc = wave & 1;
    const int lg = lane >> 4, lr = lane & 15;
    if (bid < 16) {
        const int h = bid;
        const unsigned short* A = WqcB + (size_t)h * 8192;
        const unsigned short* Bt = WukB + (size_t)h * 8192;
        f32x4 acc[4][4] = {};
#pragma unroll
        for (int kk = 0; kk < 2; ++kk) {
            short8 af[4], bfr[4];
#pragma unroll
            for (int i = 0; i < 4; i++) af[i] = *(const short8*)(A + (wr * 64 + i * 16 + lr) * 64 + kk * 32 + lg * 8);
#pragma unroll
            for (int j = 0; j < 4; j++) bfr[j] = *(const short8*)(Bt + (wc * 64 + j * 16 + lr) * 64 + kk * 32 + lg * 8);
#pragma unroll
            for (int i = 0; i < 4; i++)
#pragma unroll
                for (int j = 0; j < 4; j++)
                    acc[i][j] = __builtin_amdgcn_mfma_f32_16x16x32_bf16(af[i], bfr[j], acc[i][j], 0, 0, 0);
        }
#pragma unroll
        for (int i = 0; i < 4; i++)
#pragma unroll
            for (int j = 0; j < 4; j++)
#pragma unroll
                for (int r = 0; r < 4; r++) {
                    int row = wr * 64 + i * 16 + lg * 4 + r;   // k_in
                    int col = wc * 64 + j * 16 + lr;           // latent k'
                    Wq2T[((size_t)(h * HD2 + col)) * 128 + row] = f2bf(acc[i][j][r]);
                }
    } else {
        const int et = (bid - 16) & 15, h = (bid - 16) >> 4;
        const unsigned short* A = WoT + (size_t)et * 128 * 2048 + h * 128;
        const unsigned short* Bt = WuvB + (size_t)h * 16384;
        f32x4 acc[4][4] = {};
        auto stage = [&](int k0, int buf) {
#pragma unroll
            for (int it = 0; it < 2; ++it) {
                int e = (tid + it * 256) * 8;
                GLOAD_LDS16(A + (size_t)(e >> 5) * 2048 + k0 + (e & 31), &As[buf][0][0] + e);
            }
#pragma unroll
            for (int it = 0; it < 2; ++it) {
                int e = (tid + it * 256) * 8;
                GLOAD_LDS16(Bt + (size_t)(e >> 5) * 128 + k0 + (e & 31), &Bs[buf][0][0] + e);
            }
        };
        stage(0, 0);
        __syncthreads();
        for (int t = 0; t < 4; ++t) {
            const int cur = t & 1;
            if (t + 1 < 4) stage((t + 1) * 32, cur ^ 1);
            short8 af[4], bfr[4];
#pragma unroll
            for (int i = 0; i < 4; i++) af[i] = *(const short8*)&As[cur][wr * 64 + i * 16 + lr][lg * 8];
#pragma unroll
            for (int j = 0; j < 4; j++) bfr[j] = *(const short8*)&Bs[cur][wc * 64 + j * 16 + lr][lg * 8];
#pragma unroll
            for (int i = 0; i < 4; i++)
#pragma unroll
                for (int j = 0; j < 4; j++)
                    acc[i][j] = __builtin_amdgcn_mfma_f32_16x16x32_bf16(af[i], bfr[j], acc[i][j], 0, 0, 0);
            __syncthreads();
        }
#pragma unroll
        for (int i = 0; i < 4; i++)
#pragma unroll
            for (int j = 0; j < 4; j++)
#pragma unroll
                for (int r = 0; r < 4; r++) {
                    int row = et * 128 + wr * 64 + i * 16 + lg * 4 + r;   // e
                    int col = wc * 64 + j * 16 + lr;                      // dl
                    WeffT[(size_t)row * 2048 + h * 128 + col] = f2bf(acc[i][j][r]);
                }
    }
}

// ---------------- latent GEMM, split-K=2, BM=64: partials f32 ----------------
// P[kz][4096][320] = x[.,kz*1024:+1024] @ WcatT^T ; grid (5, 64, 2), 640 blocks.
__global__ __launch_bounds__(256) void gemm_lat_kernel(
    const float* __restrict__ A,               // [NTOK][2048] f32
    const unsigned short* __restrict__ Bt,     // WcatT [320][2048]
    float* __restrict__ P) {                   // [2][NTOK][320] f32
    constexpr int BK = 32, KH = 1024;
    __shared__ __align__(16) unsigned short As[2][64][BK];
    __shared__ __align__(16) unsigned short Bs[2][64][BK];
    const int tid = threadIdx.x, wave = tid >> 6, lane = tid & 63;
    const int wr = wave >> 1, wc = wave & 1;
    const int lg = lane >> 4, lr = lane & 15;
    const int m0 = blockIdx.y * 64, n0 = blockIdx.x * 64;
    const int kb = blockIdx.z * KH;

    f32x4 acc[2][2] = {};
    const int ar = tid >> 2, ac = (tid & 3) * 8;   // 8 f32/thread of A tile

    float4 a4[2];
    auto loadA = [&](int k0) {
        const float* src = A + (size_t)(m0 + ar) * 2048 + kb + k0 + ac;
        a4[0] = *(const float4*)(src);
        a4[1] = *(const float4*)(src + 4);
    };
    auto writeA = [&](int buf) {
        unsigned int pk[4];
        const float* f = (const float*)a4;
#pragma unroll
        for (int i = 0; i < 4; ++i)
            asm("v_cvt_pk_bf16_f32 %0, %1, %2" : "=v"(pk[i]) : "v"(f[2 * i]), "v"(f[2 * i + 1]));
        *(uint4*)&As[buf][ar][ac] = make_uint4(pk[0], pk[1], pk[2], pk[3]);
    };
    auto stageB = [&](int k0, int buf) {
        int e = tid * 8;
        GLOAD_LDS16(Bt + (size_t)(n0 + (e >> 5)) * 2048 + kb + k0 + (e & 31), &Bs[buf][0][0] + e);
    };

    loadA(0); stageB(0, 0); writeA(0);
    __syncthreads();
    constexpr int nk = KH / BK;
    for (int t = 0; t < nk; ++t) {
        const int cur = t & 1;
        if (t + 1 < nk) { loadA((t + 1) * BK); stageB((t + 1) * BK, cur ^ 1); }
        short8 af[2], bfr[2];
#pragma unroll
        for (int i = 0; i < 2; i++) af[i] = *(const short8*)&As[cur][wr * 32 + i * 16 + lr][lg * 8];
#pragma unroll
        for (int j = 0; j < 2; j++) bfr[j] = *(const short8*)&Bs[cur][wc * 32 + j * 16 + lr][lg * 8];
#pragma unroll
        for (int i = 0; i < 2; i++)
#pragma unroll
            for (int j = 0; j < 2; j++)
                acc[i][j] = __builtin_amdgcn_mfma_f32_16x16x32_bf16(af[i], bfr[j], acc[i][j], 0, 0, 0);
        if (t + 1 < nk) writeA(cur ^ 1);
        __syncthreads();
    }
#pragma unroll
    for (int i = 0; i < 2; i++)
#pragma unroll
        for (int j = 0; j < 2; j++)
#pragma unroll
            for (int r = 0; r < 4; r++) {
                int row = m0 + wr * 32 + i * 16 + lg * 4 + r;
                int col = n0 + wc * 32 + j * 16 + lr;
                P[((size_t)blockIdx.z * NTOK + row) * 320 + col] = acc[i][j][r];
            }
}

// reduce split-K partials -> g1 bf16
__global__ __launch_bounds__(256) void lat_reduce_kernel(
    const float* __restrict__ P, unsigned short* __restrict__ g1) {
    int i = (blockIdx.x * 256 + threadIdx.x) * 4;   // over 4096*320
    float4 a = *(const float4*)(P + i);
    float4 b = *(const float4*)(P + (size_t)NTOK * 320 + i);
    ushort4 o;
    o.x = f2bf(a.x + b.x); o.y = f2bf(a.y + b.y);
    o.z = f2bf(a.z + b.z); o.w = f2bf(a.w + b.w);
    *(ushort4*)(g1 + i) = o;
}

// ---------------- fused: ckv_t transpose (pre-swizzled) + rope_k ----------------
__global__ __launch_bounds__(256) void ckvt_ropek_kernel(
    unsigned short* __restrict__ g1, unsigned short* __restrict__ ckv_t,
    const float2* __restrict__ tab) {
    __shared__ unsigned short tile[64][65];
    const int bid = blockIdx.x, tid = threadIdx.x;
    if (bid < 128) {                        // ckv_t[b][dl][s] = g1[b*SS+s][dl], swizzled
        const int s0 = (bid & 31) * 64, d0 = ((bid >> 5) & 1) * 64, b = bid >> 6;
        const int tr = tid >> 4, tc = (tid & 15) * 4;
#pragma unroll
        for (int it = 0; it < 4; ++it) {
            int r = it * 16 + tr;
            *(ushort4*)&tile[r][tc] = *(const ushort4*)(g1 + (size_t)(b * SS + s0 + r) * 320 + d0 + tc);
        }
        __syncthreads();
#pragma unroll
        for (int it = 0; it < 4; ++it) {
            int r = it * 16 + tr;       // local d
            int d = d0 + r;
            ushort4 o;
            o.x = tile[tc][r]; o.y = tile[tc + 1][r]; o.z = tile[tc + 2][r]; o.w = tile[tc + 3][r];
            int chunk = tc >> 3;
            int col = ((chunk ^ (d & 7)) << 3) + (tc & 7);
            *(ushort4*)(ckv_t + ((size_t)b * 128 + d) * 2048 + s0 + col) = o;
        }
    } else {                                // rope_k: NTOK*32 elements
        int i = (bid - 128) * 256 + tid;
        int j = i & 31, row = i >> 5;
        int pos = row & (SS - 1);
        float2 cs = tab[(pos << 5) | j];
        unsigned short* p = g1 + (size_t)row * 320 + 256 + 2 * j;
        float x0 = bf2f(p[0]), x1 = bf2f(p[1]);
        p[0] = f2bf(x0 * cs.x - x1 * cs.y);
        p[1] = f2bf(x0 * cs.y + x1 * cs.x);
    }
}

// ---------------- q-projection with fused rope epilogue ----------------
__global__ __launch_bounds__(256) void gemm_q_kernel(
    const unsigned short* __restrict__ A,      // g1+128, lda 320
    const unsigned short* __restrict__ Bt,     // Wq2T [3072][128]
    unsigned short* __restrict__ C,            // q_all [NTOK][3072]
    const float2* __restrict__ tab) {
    constexpr int BM = 128, BN = 128, BK = 32;
    __shared__ __align__(16) unsigned short As[2][BM][BK];
    __shared__ __align__(16) unsigned short Bs[2][BN][BK];
    const int tid = threadIdx.x, wave = tid >> 6, lane = tid & 63;
    const int wr = wave >> 1, wc = wave & 1;
    const int lg = lane >> 4, lr = lane & 15;
    const int m0 = blockIdx.y * BM, n0 = blockIdx.x * BN;

    f32x4 acc[4][4] = {};
    auto stage = [&](int k0, int buf) {
#pragma unroll
        for (int it = 0; it < 2; ++it) {
            int e = (tid + it * 256) * 8;
            GLOAD_LDS16(A + (size_t)(m0 + (e >> 5)) * 320 + k0 + (e & 31), &As[buf][0][0] + e);
        }
#pragma unroll
        for (int it = 0; it < 2; ++it) {
            int e = (tid + it * 256) * 8;
            GLOAD_LDS16(Bt + (size_t)(n0 + (e >> 5)) * 128 + k0 + (e & 31), &Bs[buf][0][0] + e);
        }
    };
    stage(0, 0);
    __syncthreads();
    for (int t = 0; t < 4; ++t) {
        const int cur = t & 1;
        if (t + 1 < 4) stage((t + 1) * BK, cur ^ 1);
        short8 af[4], bfr[4];
#pragma unroll
        for (int i = 0; i < 4; i++) af[i] = *(const short8*)&As[cur][wr * 64 + i * 16 + lr][lg * 8];
#pragma unroll
        for (int j = 0; j < 4; j++) bfr[j] = *(const short8*)&Bs[cur][wc * 64 + j * 16 + lr][lg * 8];
#pragma unroll
        for (int i = 0; i < 4; i++)
#pragma unroll
            for (int j = 0; j < 4; j++)
                acc[i][j] = __builtin_amdgcn_mfma_f32_16x16x32_bf16(af[i], bfr[j], acc[i][j], 0, 0, 0);
        __syncthreads();
    }
#pragma unroll
    for (int i = 0; i < 4; i++)
#pragma unroll
        for (int j = 0; j < 4; j++) {
            const int colb = n0 + wc * 64 + j * 16;        // frag base (mult of 16)
            const int c6 = colb >> 6;
            const int h = (c6 * 43) >> 7;                  // colb/192 for colb<3072
            const int ch = colb - h * 192;                 // uniform per frag
#pragma unroll
            for (int r = 0; r < 4; r++) {
                int row = m0 + wr * 64 + i * 16 + lg * 4 + r;
                int col = colb + lr;
                float val = acc[i][j][r];
                if (ch >= 128) {                           // roped range (frag-uniform)
                    float partner = __shfl_xor(val, 1);
                    int jr = (ch + lr - 128) >> 1;         // pair index, same for lane pair
                    float2 cs = tab[((row & (SS - 1)) << 5) | jr];
                    val = (lr & 1) ? (partner * cs.y + val * cs.x)
                                   : (val * cs.x - partner * cs.y);
                }
                C[(size_t)row * QSTR + col] = f2bf(val);
            }
        }
}

// ---------------- out-proj: 128x256 deep-pipelined GEMM (T2+T3+T4+T5) ----------------
__global__ __launch_bounds__(512, 2) void gemm_out_kernel(
    const unsigned short* __restrict__ Ag,     // attn [4096][2048]
    const unsigned short* __restrict__ Bg,     // WeffT [2048][2048]
    float* __restrict__ C) {
    __shared__ __align__(16) unsigned short As[3][128][64];
    __shared__ __align__(16) unsigned short Bs[3][256][64];
    const int tid = threadIdx.x, wave = tid >> 6, lane = tid & 63;
    const int wr = wave >> 2, wc = wave & 3;
    const int lg = lane >> 4, lr = lane & 15;
    int id = blockIdx.y * gridDim.x + blockIdx.x;      // grid (8, 32) = 256
    int swz = (id & 7) * 32 + (id >> 3);               // bijective XCD grouping
    const int n0 = (swz & 7) * 256;
    const int m0 = (swz >> 3) * 128;

    f32x4 acc[4][4] = {};

    auto STAGE = [&](int kt, int buf) {
        const int k0 = kt * 64;
#pragma unroll
        for (int it = 0; it < 2; ++it) {               // A: 128 rows x 8 chunks
            int cid = tid + it * 512;
            int row = cid >> 3, slot = cid & 7;
            int csrc = slot ^ (row & 7);
            GLOAD_LDS16(Ag + (size_t)(m0 + row) * 2048 + k0 + csrc * 8, &As[buf][0][0] + cid * 8);
        }
#pragma unroll
        for (int it = 0; it < 4; ++it) {               // B: 256 rows x 8 chunks
            int cid = tid + it * 512;
            int row = cid >> 3, slot = cid & 7;
            int csrc = slot ^ (row & 7);
            GLOAD_LDS16(Bg + (size_t)(n0 + row) * 2048 + k0 + csrc * 8, &Bs[buf][0][0] + cid * 8);
        }
    };
    auto compute = [&](int buf) {
#pragma unroll
        for (int ks = 0; ks < 2; ++ks) {
            const int ca = ((ks * 4 + lg) ^ (lr & 7)) * 8;   // swizzled read chunk
            short8 af[4], bfr[4];
#pragma unroll
            for (int i = 0; i < 4; i++) af[i] = *(const short8*)&As[buf][wr * 64 + i * 16 + lr][ca];
#pragma unroll
            for (int j = 0; j < 4; j++) bfr[j] = *(const short8*)&Bs[buf][wc * 64 + j * 16 + lr][ca];
            __builtin_amdgcn_s_setprio(1);
#pragma unroll
            for (int i = 0; i < 4; i++)
#pragma unroll
                for (int j = 0; j < 4; j++)
                    acc[i][j] = __builtin_amdgcn_mfma_f32_16x16x32_bf16(af[i], bfr[j], acc[i][j], 0, 0, 0);
            __builtin_amdgcn_s_setprio(0);
        }
    };

    STAGE(0, 0); STAGE(1, 1); STAGE(2, 2);             // 18 loads in flight
    for (int t = 0; t < 30; ++t) {
        asm volatile("s_waitcnt vmcnt(12)" ::: "memory");
        __builtin_amdgcn_s_barrier();
        asm volatile("" ::: "memory");
        compute(t % 3);
        asm volatile("" ::: "memory");
        __builtin_amdgcn_s_barrier();
        if (t < 29) STAGE(t + 3, t % 3);
    }
    asm volatile("s_waitcnt vmcnt(6)" ::: "memory");
    __builtin_amdgcn_s_barrier();
    asm volatile("" ::: "memory");
    compute(0);
    asm volatile("" ::: "memory");
    __builtin_amdgcn_s_barrier();
    asm volatile("s_waitcnt vmcnt(0)" ::: "memory");
    __builtin_amdgcn_s_barrier();
    asm volatile("" ::: "memory");
    compute(1);

#pragma unroll
    for (int i = 0; i < 4; i++)
#pragma unroll
        for (int j = 0; j < 4; j++)
#pragma unroll
            for (int r = 0; r < 4; r++) {
                int row = m0 + wr * 64 + i * 16 + lg * 4 + r;
                int col = n0 + wc * 64 + j * 16 + lr;
                C[(size_t)row * 2048 + col] = acc[i][j][r];
            }
}

// ---------------- flash attention v10: 3-buffer counted-vmcnt pipeline ----------------
__global__ __launch_bounds__(512) void mla_attn_kernel(
    const unsigned short* __restrict__ q_all,   // [NTOK][3072]: per head [qtil(128)|qrope(64)]
    const unsigned short* __restrict__ g1,      // [NTOK][320]: ckv 0..127, roped k_r 256..319
    const unsigned short* __restrict__ ckv_t,   // [2][128][2048] chunk-swizzled
    unsigned short* __restrict__ attn_out,      // [NTOK][2048] (o_lat)
    unsigned short* __restrict__ partOb,        // [256 pair][2 side][128 q][128 d] bf16
    float* __restrict__ partL,
    float* __restrict__ partM) {
    __shared__ __align__(16) char smem[122880];
    auto Ks = (unsigned short (*)[64][192])smem;             // [3][64][192], chunk-swizzled
    auto Vs = (unsigned short (*)[128][64])(smem + 73728);   // [3][128][64], chunk-swizzled

    const int id = blockIdx.x;
    const int xcd = id & 7, loc = id >> 3;
    const int hp = 2 * xcd + (loc >> 4);        // head-pair 0..15
    const int s2 = loc & 15;
    const bool roleA = s2 < 8;
    const int qb = roleA ? s2 : s2 - 8;
    const int hiqb = 15 - qb, xsp = 15 - 2 * qb;
    const int b = hp >> 3;
    const int tid = threadIdx.x, wave = tid >> 6, lane = tid & 63;
    const int wg = wave & 3, hsel = wave >> 2;
    const int h = (hp & 7) * 2 + hsel;
    const int bh = b * 16 + h;
    const int pairIdx = bh * 8 + qb;
    const int ql = lane & 31, hb = lane >> 5;
    const int kvB = b * SS;
    const float sc2 = 0.12751744f;   // (1/sqrt(128)) * log2(e)
    const int xh = ql & 7;

    auto stageK = [&](int t, int bufi) {       // 3 gload_lds / thread
#pragma unroll
        for (int it = 0; it < 3; ++it) {
            int cid = tid + it * 512;
            int r = cid / 24, s = cid - r * 24;
            int c = s ^ (r & 7);
            int col = (c < 16) ? c * 8 : 256 + (c - 16) * 8;
            GLOAD_LDS16(g1 + (size_t)(kvB + t * 64 + r) * 320 + col,
                        &Ks[bufi][0][0] + cid * 8);
        }
    };
    auto stageV = [&](int t, int bufi) {       // 2 gload_lds / thread (src pre-swizzled)
#pragma unroll
        for (int it = 0; it < 2; ++it) {
            int e = tid * 8 + it * 4096;
            GLOAD_LDS16(ckv_t + ((size_t)b * 128 + (e >> 6)) * 2048 + t * 64 + (e & 63),
                        &Vs[bufi][0][0] + e);
        }
    };

    auto run = [&](int q0, int t0, int cnt, bool direct, int side) {
        __syncthreads();                       // fence prior smem use (drains prior vmem too)
        const int q0w = q0 + wg * 32;
        const int qg = q0w + ql;

        short8 qf[12];
        {
            const unsigned short* qp = q_all + (size_t)(kvB + qg) * QSTR + h * HD2 + hb * 8;
#pragma unroll
            for (int ss = 0; ss < 12; ++ss) qf[ss] = *(const short8*)(qp + 16 * ss);
        }
        f32x16 o[4] = {};
        float m_raw = -3e38f, mb = 0.f, l_r = 0.f;

        stageK(t0, 0); stageV(t0, 0);
        if (cnt > 1) { stageK(t0 + 1, 1); stageV(t0 + 1, 1); }
        if (cnt > 2) { stageK(t0 + 2, 2); stageV(t0 + 2, 2); }

        for (int tt = 0; tt < cnt; ++tt) {
            const int t = t0 + tt;
            const int cur = tt % 3;
            int ahead = cnt - tt - 1; if (ahead > 2) ahead = 2;
            if (ahead == 2)      asm volatile("s_waitcnt vmcnt(10)" ::: "memory");
            else if (ahead == 1) asm volatile("s_waitcnt vmcnt(5)" ::: "memory");
            else                 asm volatile("s_waitcnt vmcnt(0)" ::: "memory");
            __builtin_amdgcn_s_barrier();       // tile tt landed for ALL waves
            asm volatile("" ::: "memory");
            {
                f32x16 p0 = {}, p1 = {};
                __builtin_amdgcn_s_setprio(1);
#pragma unroll
                for (int ss = 0; ss < 12; ++ss) {
                    int pc = (((2 * ss + hb) ^ xh) << 3);
                    short8 k0 = *(const short8*)&Ks[cur][ql][pc];
                    short8 k1 = *(const short8*)&Ks[cur][32 + ql][pc];
                    p0 = __builtin_amdgcn_mfma_f32_32x32x16_bf16(k0, qf[ss], p0, 0, 0, 0);
                    p1 = __builtin_amdgcn_mfma_f32_32x32x16_bf16(k1, qf[ss], p1, 0, 0, 0);
                }
                __builtin_amdgcn_s_setprio(0);
                const int kv0 = t * 64;
                if (kv0 + 63 > q0w) {
#pragma unroll
                    for (int r = 0; r < 16; ++r) {
                        int kvg = kv0 + (r & 3) + 8 * (r >> 2) + 4 * hb;
                        if (kvg > qg) p0[r] = -3e38f;
                        if (kvg + 32 > qg) p1[r] = -3e38f;
                    }
                }
                float pm = -3e38f;
#pragma unroll
                for (int r = 0; r < 16; ++r) pm = fmaxf(pm, fmaxf(p0[r], p1[r]));
                pm = fmaxf(pm, __shfl_xor(pm, 32));
                if (__any(pm > m_raw + 64.f)) {   // defer-max (T13)
                    float mn = fmaxf(m_raw, pm);
                    float alpha = exp2f((m_raw - mn) * sc2);
                    m_raw = mn; mb = mn * sc2;
                    l_r *= alpha;
#pragma unroll
                    for (int dt = 0; dt < 4; ++dt)
#pragma unroll
                        for (int r = 0; r < 16; ++r) o[dt][r] *= alpha;
                }
                float ps = 0.f;
#pragma unroll
                for (int r = 0; r < 16; ++r) {
                    p0[r] = exp2f(__builtin_fmaf(p0[r], sc2, -mb));
                    p1[r] = exp2f(__builtin_fmaf(p1[r], sc2, -mb));
                    ps += p0[r] + p1[r];
                }
                l_r += ps;
                unsigned int pk0[8], pk1[8];
#pragma unroll
                for (int i = 0; i < 8; ++i) {
                    asm("v_cvt_pk_bf16_f32 %0, %1, %2" : "=v"(pk0[i]) : "v"(p0[2 * i]), "v"(p0[2 * i + 1]));
                    asm("v_cvt_pk_bf16_f32 %0, %1, %2" : "=v"(pk1[i]) : "v"(p1[2 * i]), "v"(p1[2 * i + 1]));
                }
                uint4 bfr[4];
#pragma unroll
                for (int sg = 0; sg < 2; ++sg) {
                    unsigned int x0 = pk0[4 * sg], y0 = pk0[4 * sg + 2];
                    asm volatile("v_permlane32_swap_b32 %0, %1" : "+v"(x0), "+v"(y0));
                    unsigned int x1 = pk0[4 * sg + 1], y1 = pk0[4 * sg + 3];
                    asm volatile("v_permlane32_swap_b32 %0, %1" : "+v"(x1), "+v"(y1));
                    bfr[sg] = make_uint4(x0, x1, y0, y1);
                    unsigned int x2 = pk1[4 * sg], y2 = pk1[4 * sg + 2];
                    asm volatile("v_permlane32_swap_b32 %0, %1" : "+v"(x2), "+v"(y2));
                    unsigned int x3 = pk1[4 * sg + 1], y3 = pk1[4 * sg + 3];
                    asm volatile("v_permlane32_swap_b32 %0, %1" : "+v"(x3), "+v"(y3));
                    bfr[2 + sg] = make_uint4(x2, x3, y2, y3);
                }
                __builtin_amdgcn_s_setprio(1);
#pragma unroll
                for (int ss = 0; ss < 4; ++ss) {
                    short8 pb = __builtin_bit_cast(short8, bfr[ss]);
                    int vc = (((2 * ss + hb) ^ xh) << 3);
#pragma unroll
                    for (int dt = 0; dt < 4; ++dt) {
                        short8 vf = *(const short8*)&Vs[cur][dt * 32 + ql][vc];
                        o[dt] = __builtin_amdgcn_mfma_f32_32x32x16_bf16(vf, pb, o[dt], 0, 0, 0);
                    }
                }
                __builtin_amdgcn_s_setprio(0);
            }
            asm volatile("" ::: "memory");
            __builtin_amdgcn_s_barrier();       // all waves done reading buf cur
            if (tt + 3 < cnt) { stageK(t + 3, cur); stageV(t + 3, cur); }
        }

        l_r += __shfl_xor(l_r, 32);
        if (direct) {
            float inv_l = 1.f / l_r;
            unsigned int* ep = (unsigned int*)smem + wave * 2176;
#pragma unroll
            for (int dt = 0; dt < 4; ++dt)
#pragma unroll
                for (int r = 0; r < 16; r += 2) {
                    float a = o[dt][r] * inv_l, c2 = o[dt][r + 1] * inv_l;
                    unsigned int pkv;
                    asm("v_cvt_pk_bf16_f32 %0, %1, %2" : "=v"(pkv) : "v"(a), "v"(c2));
                    ep[ql * 68 + dt * 16 + ((r & 3) >> 1) + 4 * (r >> 2) + 2 * hb] = pkv;
                }
#pragma unroll
            for (int it = 0; it < 8; ++it) {
                int qr = lane >> 1, ch = (lane & 1) * 8 + it;
                uint4 w = *(uint4*)&ep[qr * 68 + ch * 4];
                *(uint4*)(attn_out + (size_t)(kvB + q0w + qr) * 2048 + h * 128 + ch * 8) = w;
            }
        } else {
            float* sW = (float*)smem + wg * 4224;
            const size_t pb2 = ((size_t)pairIdx * 2 + side);
#pragma unroll
            for (int pass = 0; pass < 2; ++pass) {
                if (pass == 1) __syncthreads();
                if (hsel == pass) {
#pragma unroll
                    for (int dt = 0; dt < 4; ++dt)
#pragma unroll
                        for (int r = 0; r < 16; ++r)
                            sW[ql * 132 + dt * 32 + (r & 3) + 8 * (r >> 2) + 4 * hb] = o[dt][r];
                    int q = lane >> 1, half = lane & 1;
                    const float* src = sW + q * 132 + half * 64;
                    unsigned int* dst = (unsigned int*)(partOb + pb2 * 16384 + ((size_t)(wg * 32 + q)) * 128 + half * 64);
#pragma unroll
                    for (int j = 0; j < 64; j += 4) {
                        float4 f = *(const float4*)(src + j);
                        unsigned int d0, d1;
                        asm("v_cvt_pk_bf16_f32 %0, %1, %2" : "=v"(d0) : "v"(f.x), "v"(f.y));
                        asm("v_cvt_pk_bf16_f32 %0, %1, %2" : "=v"(d1) : "v"(f.z), "v"(f.w));
                        *(uint2*)(dst + (j >> 1)) = make_uint2(d0, d1);
                    }
                    if (hb == 0) {
                        partL[pb2 * 128 + wg * 32 + ql] = l_r;
                        partM[pb2 * 128 + wg * 32 + ql] = m_raw;
                    }
                }
            }
        }
    };

    if (roleA) {
        run(qb * 128, 0, 2 * qb + 2, true, 0);
        run(hiqb * 128, 0, xsp, false, 0);
    } else {
        run(hiqb * 128, xsp, 17, false, 1);
    }
}

// merge the two partials of each hi q-tile (bf16 partO)
__global__ __launch_bounds__(256) void merge_kernel(
    const unsigned short* __restrict__ partOb, const float* __restrict__ partL,
    const float* __restrict__ partM, unsigned short* __restrict__ attn_out) {
    __shared__ float sA[128], sB[128], sI[128];
    const int p = blockIdx.x, tid = threadIdx.x;
    const int bh = p >> 3, qb = p & 7;
    const int b = bh >> 4, h = bh & 15;
    const int q0 = (15 - qb) * 128;
    const float sc2 = 0.12751744f;
    if (tid < 128) {
        float mA = partM[(size_t)(p * 2) * 128 + tid];
        float mB = partM[(size_t)(p * 2 + 1) * 128 + tid];
        float mM = fmaxf(mA, mB);
        float aA = exp2f((mA - mM) * sc2), aB = exp2f((mB - mM) * sc2);
        float lT = aA * partL[(size_t)(p * 2) * 128 + tid] + aB * partL[(size_t)(p * 2 + 1) * 128 + tid];
        sA[tid] = aA; sB[tid] = aB; sI[tid] = 1.f / lT;
    }
    __syncthreads();
    const int q = tid >> 1, half = tid & 1;
    const float aA = sA[q], aB = sB[q], inv = sI[q];
    const unsigned short* oA = partOb + (size_t)(p * 2) * 16384 + q * 128 + half * 64;
    const unsigned short* oB = partOb + (size_t)(p * 2 + 1) * 16384 + q * 128 + half * 64;
    unsigned short* dst = attn_out + (size_t)(b * SS + q0 + q) * 2048 + h * 128 + half * 64;
#pragma unroll
    for (int j = 0; j < 64; j += 4) {
        ushort4 ua = *(const ushort4*)(oA + j);
        ushort4 ub = *(const ushort4*)(oB + j);
        ushort4 u;
        u.x = f2bf((aA * bf2f(ua.x) + aB * bf2f(ub.x)) * inv);
        u.y = f2bf((aA * bf2f(ua.y) + aB * bf2f(ub.y)) * inv);
        u.z = f2bf((aA * bf2f(ua.z) + aB * bf2f(ub.z)) * inv);
        u.w = f2bf((aA * bf2f(ua.w) + aB * bf2f(ub.w)) * inv);
        *(ushort4*)(dst + j) = u;
    }
}

// ---------------- launcher ----------------

extern "C" void kernel_launch(void* const* d_in, const int* in_sizes, int n_in,
                              void* d_out, int out_size, void* d_ws, size_t ws_size,
                              hipStream_t stream) {
    const float* x     = (const float*)d_in[0];
    const float* W_dkv = (const float*)d_in[1];
    const float* W_dq  = (const float*)d_in[2];
    const float* W_kr  = (const float*)d_in[3];
    const float* W_qc  = (const float*)d_in[4];
    const float* W_qr  = (const float*)d_in[5];
    const float* W_uk  = (const float*)d_in[6];
    const float* W_uv  = (const float*)d_in[7];
    const float* W_o   = (const float*)d_in[8];
    float* out = (float*)d_out;

    size_t off = 0;
    auto alloc = [&](size_t bytes) {
        void* p = (char*)d_ws + off;
        off = (off + bytes + 255) & ~(size_t)255;
        return p;
    };
    unsigned short* WcatT = (unsigned short*)alloc((size_t)320 * 2048 * 2);
    unsigned short* Wq2T  = (unsigned short*)alloc((size_t)3072 * 128 * 2);
    unsigned short* WqcB  = (unsigned short*)alloc((size_t)16 * 128 * 64 * 2);
    unsigned short* WukB  = (unsigned short*)alloc((size_t)16 * 128 * 64 * 2);
    unsigned short* WuvB  = (unsigned short*)alloc((size_t)16 * 128 * 128 * 2);
    unsigned short* WoT   = (unsigned short*)alloc((size_t)2048 * 2048 * 2);
    unsigned short* WeffT = (unsigned short*)alloc((size_t)2048 * 2048 * 2);
    unsigned short* g1    = (unsigned short*)alloc((size_t)NTOK * 320 * 2);
    unsigned short* q_all = (unsigned short*)alloc((size_t)NTOK * QSTR * 2);
    unsigned short* ckv_t = (unsigned short*)alloc((size_t)2 * 128 * 2048 * 2);
    unsigned short* attn  = (unsigned short*)alloc((size_t)NTOK * 2048 * 2);
    float2* rope_tab      = (float2*)alloc((size_t)SS * 32 * sizeof(float2));
    unsigned short* partOb= (unsigned short*)alloc((size_t)256 * 2 * 16384 * 2);
    float* partL          = (float*)alloc((size_t)256 * 2 * 128 * 4);
    float* partM          = (float*)alloc((size_t)256 * 2 * 128 * 4);
    float* latP           = (float*)alloc((size_t)2 * NTOK * 320 * 4);

    // 1: layouts (all-coalesced) + rope table
    prep_kernel<<<1984, 256, 0, stream>>>(W_dkv, W_dq, W_kr, W_qc, W_qr, W_uk, W_uv, W_o,
                                          WcatT, Wq2T, WqcB, WukB, WuvB, WoT, rope_tab);
    // 2: absorbed-weight precomputes (wqk + weff fused)
    weights2_kernel<<<16 + 256, 256, 0, stream>>>(WqcB, WukB, Wq2T, WoT, WuvB, WeffT);
    // 3: latent GEMM split-K=2 (f32 A, conversion folded) + reduce
    gemm_lat_kernel<<<dim3(5, 64, 2), 256, 0, stream>>>(x, WcatT, latP);
    lat_reduce_kernel<<<NTOK * 320 / 1024, 256, 0, stream>>>(latP, g1);
    // 4: c_kv transpose (pre-swizzled) + k-rope
    ckvt_ropek_kernel<<<128 + 512, 256, 0, stream>>>(g1, ckv_t, rope_tab);
    // 5: absorbed q projection with fused q-rope epilogue
    gemm_q_kernel<<<dim3(24, 32), 256, 0, stream>>>(g1 + 128, Wq2T, q_all, rope_tab);
    // 6: attention (3-buffer counted-vmcnt pipeline) + merge
    mla_attn_kernel<<<256, 512, 0, stream>>>(q_all, g1, ckv_t, attn, partOb, partL, partM);
    merge_kernel<<<256, 256, 0, stream>>>(partOb, partL, partM, attn);
    // 7: output projection with W_eff -> fp32 (deep-pipelined)
    gemm_out_kernel<<<dim3(8, 32), 512, 0, stream>>>(attn, WeffT, out);
}

// Round 16
// 194.424 us; speedup vs baseline: 1.1704x; 1.0253x over previous
//
#include <hip/hip_runtime.h>
#include <hip/hip_bf16.h>

typedef __attribute__((ext_vector_type(8))) short short8;
typedef __attribute__((ext_vector_type(4))) float f32x4;
typedef __attribute__((ext_vector_type(16))) float f32x16;

#define N_EMBED 2048
#define N_HEAD 16
#define BB 2
#define SS 2048
#define NTOK (BB*SS)          // 4096
#define HD2 192               // absorbed head dim: 128 latent + 64 rope
#define QSTR 3072             // q_all row stride = 16*192

__device__ __forceinline__ unsigned short f2bf(float f) {
    unsigned int b = __builtin_bit_cast(unsigned int, f);
    b += 0x7fffu + ((b >> 16) & 1u);
    return (unsigned short)(b >> 16);
}
__device__ __forceinline__ float bf2f(unsigned short u) {
    unsigned int b = ((unsigned int)u) << 16;
    return __builtin_bit_cast(float, b);
}

#define GLOAD_LDS16(gsrc, ldst) __builtin_amdgcn_global_load_lds( \
    (const __attribute__((address_space(1))) void*)(gsrc), \
    (__attribute__((address_space(3))) void*)(ldst), 16, 0, 0)

#define ROPE_COEF (-0.28782313662425575f)  // -ln(10000)/32

// ---------------- prep: all-coalesced layouts + rope table ----------------
__global__ __launch_bounds__(256) void prep_kernel(
    const float* __restrict__ Wdkv, const float* __restrict__ Wdq, const float* __restrict__ Wkr,
    const float* __restrict__ Wqc, const float* __restrict__ Wqr,
    const float* __restrict__ Wuk, const float* __restrict__ Wuv, const float* __restrict__ Wo,
    unsigned short* __restrict__ WcatT, unsigned short* __restrict__ Wq2T,
    unsigned short* __restrict__ WqcB, unsigned short* __restrict__ WukB,
    unsigned short* __restrict__ WuvB, unsigned short* __restrict__ WoT,
    float2* __restrict__ rope_tab) {
    __shared__ float tile[64][65];
    const int bid = blockIdx.x, tid = threadIdx.x;
    const int tr = tid >> 4, tc = (tid & 15) * 4;
    if (bid < 160) {                        // WcatT [320][2048] via tiled transpose
        const int k0 = (bid & 31) * 64, n0 = (bid >> 5) * 64;
        const float* W; int base, width;
        if (n0 < 128)      { W = Wdkv; base = 0;   width = 128; }
        else if (n0 < 256) { W = Wdq;  base = 128; width = 128; }
        else               { W = Wkr;  base = 256; width = 64; }
#pragma unroll
        for (int it = 0; it < 4; ++it) {
            int r = it * 16 + tr;
            float4 v = *(const float4*)(W + (size_t)(k0 + r) * width + (n0 - base) + tc);
            tile[r][tc] = v.x; tile[r][tc + 1] = v.y; tile[r][tc + 2] = v.z; tile[r][tc + 3] = v.w;
        }
        __syncthreads();
#pragma unroll
        for (int it = 0; it < 4; ++it) {
            int r = it * 16 + tr;           // n-local
            ushort4 o;
            o.x = f2bf(tile[tc][r]); o.y = f2bf(tile[tc + 1][r]);
            o.z = f2bf(tile[tc + 2][r]); o.w = f2bf(tile[tc + 3][r]);
            *(ushort4*)(WcatT + (size_t)(n0 + r) * 2048 + k0 + tc) = o;
        }
    } else if (bid < 192) {                 // Wq2T rope rows: transpose Wqr[h] (128k x 64jr)
        const int tb = bid - 160;
        const int h = tb >> 1, k0 = (tb & 1) * 64;
#pragma unroll
        for (int it = 0; it < 4; ++it) {
            int r = it * 16 + tr;           // k-local
            float4 v = *(const float4*)(Wqr + (size_t)(h * 128 + k0 + r) * 64 + tc);
            tile[r][tc] = v.x; tile[r][tc + 1] = v.y; tile[r][tc + 2] = v.z; tile[r][tc + 3] = v.w;
        }
        __syncthreads();
#pragma unroll
        for (int it = 0; it < 4; ++it) {
            int rr = it * 16 + tr;          // jr
            ushort4 o;
            o.x = f2bf(tile[tc][rr]); o.y = f2bf(tile[tc + 1][rr]);
            o.z = f2bf(tile[tc + 2][rr]); o.w = f2bf(tile[tc + 3][rr]);
            *(ushort4*)(Wq2T + (size_t)(h * HD2 + 128 + rr) * 128 + k0 + tc) = o;
        }
    } else if (bid < 320) {                 // WqcB copy [16][128][64]
        int i = (bid - 192) * 1024 + tid * 4;
        float4 v = *(const float4*)(Wqc + i);
        ushort4 o; o.x = f2bf(v.x); o.y = f2bf(v.y); o.z = f2bf(v.z); o.w = f2bf(v.w);
        *(ushort4*)(WqcB + i) = o;
    } else if (bid < 448) {                 // WukB copy
        int i = (bid - 320) * 1024 + tid * 4;
        float4 v = *(const float4*)(Wuk + i);
        ushort4 o; o.x = f2bf(v.x); o.y = f2bf(v.y); o.z = f2bf(v.z); o.w = f2bf(v.w);
        *(ushort4*)(WukB + i) = o;
    } else if (bid < 704) {                 // WuvB copy [16][128][128]
        int i = (bid - 448) * 1024 + tid * 4;
        float4 v = *(const float4*)(Wuv + i);
        ushort4 o; o.x = f2bf(v.x); o.y = f2bf(v.y); o.z = f2bf(v.z); o.w = f2bf(v.w);
        *(ushort4*)(WuvB + i) = o;
    } else if (bid < 1728) {                // WoT [2048][2048] tiled transpose
        int tb = bid - 704;
        const int k0 = (tb & 31) * 64, n0 = (tb >> 5) * 64;
#pragma unroll
        for (int it = 0; it < 4; ++it) {
            int r = it * 16 + tr;
            float4 v = *(const float4*)(Wo + (size_t)(k0 + r) * 2048 + n0 + tc);
            tile[r][tc] = v.x; tile[r][tc + 1] = v.y; tile[r][tc + 2] = v.z; tile[r][tc + 3] = v.w;
        }
        __syncthreads();
#pragma unroll
        for (int it = 0; it < 4; ++it) {
            int r = it * 16 + tr;
            ushort4 o;
            o.x = f2bf(tile[tc][r]); o.y = f2bf(tile[tc + 1][r]);
            o.z = f2bf(tile[tc + 2][r]); o.w = f2bf(tile[tc + 3][r]);
            *(ushort4*)(WoT + (size_t)(n0 + r) * 2048 + k0 + tc) = o;
        }
    } else {                                // rope table [SS][32]
        int i = (bid - 1728) * 256 + tid;
        int pos = i >> 5, j = i & 31;
        float freq = __expf(ROPE_COEF * (float)j);
        float a = (float)pos * freq;
        float s, c;
        __sincosf(a, &s, &c);
        rope_tab[i] = make_float2(c, s);
    }
}

// ---------------- fused2: weight GEMMs (bid<272) + latent split-K GEMM (bid 272-911) ----------------
__global__ __launch_bounds__(256) void fused2_kernel(
    const unsigned short* __restrict__ WqcB, const unsigned short* __restrict__ WukB,
    unsigned short* __restrict__ Wq2T,
    const unsigned short* __restrict__ WoT, const unsigned short* __restrict__ WuvB,
    unsigned short* __restrict__ WeffT,
    const float* __restrict__ A,               // x [NTOK][2048] f32
    const unsigned short* __restrict__ Bt,     // WcatT [320][2048]
    float* __restrict__ P) {                   // [2][NTOK][320] f32
    __shared__ __align__(16) unsigned short As[2][128][32];
    __shared__ __align__(16) unsigned short Bs[2][128][32];
    const int bid = blockIdx.x;
    const int tid = threadIdx.x, wave = tid >> 6, lane = tid & 63;
    const int wr = wave >> 1, wc = wave & 1;
    const int lg = lane >> 4, lr = lane & 15;
    if (bid < 16) {
        // W_qk[h] = W_qc[h] @ W_uk[h]^T
        const int h = bid;
        const unsigned short* Aq = WqcB + (size_t)h * 8192;
        const unsigned short* Btq = WukB + (size_t)h * 8192;
        f32x4 acc[4][4] = {};
#pragma unroll
        for (int kk = 0; kk < 2; ++kk) {
            short8 af[4], bfr[4];
#pragma unroll
            for (int i = 0; i < 4; i++) af[i] = *(const short8*)(Aq + (wr * 64 + i * 16 + lr) * 64 + kk * 32 + lg * 8);
#pragma unroll
            for (int j = 0; j < 4; j++) bfr[j] = *(const short8*)(Btq + (wc * 64 + j * 16 + lr) * 64 + kk * 32 + lg * 8);
#pragma unroll
            for (int i = 0; i < 4; i++)
#pragma unroll
                for (int j = 0; j < 4; j++)
                    acc[i][j] = __builtin_amdgcn_mfma_f32_16x16x32_bf16(af[i], bfr[j], acc[i][j], 0, 0, 0);
        }
#pragma unroll
        for (int i = 0; i < 4; i++)
#pragma unroll
            for (int j = 0; j < 4; j++)
#pragma unroll
                for (int r = 0; r < 4; r++) {
                    int row = wr * 64 + i * 16 + lg * 4 + r;
                    int col = wc * 64 + j * 16 + lr;
                    Wq2T[((size_t)(h * HD2 + col)) * 128 + row] = f2bf(acc[i][j][r]);
                }
    } else if (bid < 272) {
        // W_effT[e][h*128+dl] = sum_dh WuvB[h][dl][dh] * WoT[e][h*128+dh]
        const int et = (bid - 16) & 15, h = (bid - 16) >> 4;
        const unsigned short* Aw = WoT + (size_t)et * 128 * 2048 + h * 128;
        const unsigned short* Btw = WuvB + (size_t)h * 16384;
        f32x4 acc[4][4] = {};
        auto stage = [&](int k0, int buf) {
#pragma unroll
            for (int it = 0; it < 2; ++it) {
                int e = (tid + it * 256) * 8;
                GLOAD_LDS16(Aw + (size_t)(e >> 5) * 2048 + k0 + (e & 31), &As[buf][0][0] + e);
            }
#pragma unroll
            for (int it = 0; it < 2; ++it) {
                int e = (tid + it * 256) * 8;
                GLOAD_LDS16(Btw + (size_t)(e >> 5) * 128 + k0 + (e & 31), &Bs[buf][0][0] + e);
            }
        };
        stage(0, 0);
        __syncthreads();
        for (int t = 0; t < 4; ++t) {
            const int cur = t & 1;
            if (t + 1 < 4) stage((t + 1) * 32, cur ^ 1);
            short8 af[4], bfr[4];
#pragma unroll
            for (int i = 0; i < 4; i++) af[i] = *(const short8*)&As[cur][wr * 64 + i * 16 + lr][lg * 8];
#pragma unroll
            for (int j = 0; j < 4; j++) bfr[j] = *(const short8*)&Bs[cur][wc * 64 + j * 16 + lr][lg * 8];
#pragma unroll
            for (int i = 0; i < 4; i++)
#pragma unroll
                for (int j = 0; j < 4; j++)
                    acc[i][j] = __builtin_amdgcn_mfma_f32_16x16x32_bf16(af[i], bfr[j], acc[i][j], 0, 0, 0);
            __syncthreads();
        }
#pragma unroll
        for (int i = 0; i < 4; i++)
#pragma unroll
            for (int j = 0; j < 4; j++)
#pragma unroll
                for (int r = 0; r < 4; r++) {
                    int row = et * 128 + wr * 64 + i * 16 + lg * 4 + r;
                    int col = wc * 64 + j * 16 + lr;
                    WeffT[(size_t)row * 2048 + h * 128 + col] = f2bf(acc[i][j][r]);
                }
    } else {
        // latent GEMM split-K=2, BM=64 (FLAT LDS indexing: row*32+col)
        const int t0 = bid - 272;
        const int kz = t0 / 320, rem = t0 - kz * 320;
        const int by = rem / 5, bx = rem - by * 5;
        constexpr int BK = 32, KH = 1024;
        const int m0 = by * 64, n0 = bx * 64;
        const int kb = kz * KH;
        f32x4 acc[2][2] = {};
        const int ar = tid >> 2, ac = (tid & 3) * 8;
        float4 a4[2];
        auto loadA = [&](int k0) {
            const float* src = A + (size_t)(m0 + ar) * 2048 + kb + k0 + ac;
            a4[0] = *(const float4*)(src);
            a4[1] = *(const float4*)(src + 4);
        };
        auto writeA = [&](int buf) {
            unsigned int pk[4];
            const float* f = (const float*)a4;
#pragma unroll
            for (int i = 0; i < 4; ++i)
                asm("v_cvt_pk_bf16_f32 %0, %1, %2" : "=v"(pk[i]) : "v"(f[2 * i]), "v"(f[2 * i + 1]));
            *(uint4*)(&As[buf][0][0] + ar * 32 + ac) = make_uint4(pk[0], pk[1], pk[2], pk[3]);
        };
        auto stageB = [&](int k0, int buf) {
            int e = tid * 8;
            GLOAD_LDS16(Bt + (size_t)(n0 + (e >> 5)) * 2048 + kb + k0 + (e & 31), &Bs[buf][0][0] + e);
        };
        loadA(0); stageB(0, 0); writeA(0);
        __syncthreads();
        constexpr int nk = KH / BK;
        for (int t = 0; t < nk; ++t) {
            const int cur = t & 1;
            if (t + 1 < nk) { loadA((t + 1) * BK); stageB((t + 1) * BK, cur ^ 1); }
            short8 af[2], bfr[2];
#pragma unroll
            for (int i = 0; i < 2; i++)
                af[i] = *(const short8*)(&As[cur][0][0] + (wr * 32 + i * 16 + lr) * 32 + lg * 8);
#pragma unroll
            for (int j = 0; j < 2; j++)
                bfr[j] = *(const short8*)(&Bs[cur][0][0] + (wc * 32 + j * 16 + lr) * 32 + lg * 8);
#pragma unroll
            for (int i = 0; i < 2; i++)
#pragma unroll
                for (int j = 0; j < 2; j++)
                    acc[i][j] = __builtin_amdgcn_mfma_f32_16x16x32_bf16(af[i], bfr[j], acc[i][j], 0, 0, 0);
            if (t + 1 < nk) writeA(cur ^ 1);
            __syncthreads();
        }
#pragma unroll
        for (int i = 0; i < 2; i++)
#pragma unroll
            for (int j = 0; j < 2; j++)
#pragma unroll
                for (int r = 0; r < 4; r++) {
                    int row = m0 + wr * 32 + i * 16 + lg * 4 + r;
                    int col = n0 + wc * 32 + j * 16 + lr;
                    P[((size_t)kz * NTOK + row) * 320 + col] = acc[i][j][r];
                }
    }
}

// reduce split-K partials -> g1 bf16
__global__ __launch_bounds__(256) void lat_reduce_kernel(
    const float* __restrict__ P, unsigned short* __restrict__ g1) {
    int i = (blockIdx.x * 256 + threadIdx.x) * 4;   // over 4096*320
    float4 a = *(const float4*)(P + i);
    float4 b = *(const float4*)(P + (size_t)NTOK * 320 + i);
    ushort4 o;
    o.x = f2bf(a.x + b.x); o.y = f2bf(a.y + b.y);
    o.z = f2bf(a.z + b.z); o.w = f2bf(a.w + b.w);
    *(ushort4*)(g1 + i) = o;
}

// ---------------- fused3: ckvt (bid<128) + rope_k (128-639) + q-proj (640-1407) ----------------
// sm[2][256][32]: q-proj buf = A tile rows 0..127 (flat 0..4095) + B tile rows 128..255.
__global__ __launch_bounds__(256) void fused3_kernel(
    unsigned short* __restrict__ g1, unsigned short* __restrict__ ckv_t,
    const float2* __restrict__ tab,
    const unsigned short* __restrict__ Aq,     // g1+128, lda 320
    const unsigned short* __restrict__ Btq,    // Wq2T [3072][128]
    unsigned short* __restrict__ C) {          // q_all [NTOK][3072]
    __shared__ __align__(16) unsigned short sm[2][256][32];   // 32KB
    const int bid = blockIdx.x, tid = threadIdx.x;
    if (bid < 128) {                        // ckv_t[b][dl][s] = g1[b*SS+s][dl], swizzled
        unsigned short (*tile)[65] = (unsigned short (*)[65])&sm[0][0][0];  // 8320 <= 16384 elems
        const int s0 = (bid & 31) * 64, d0 = ((bid >> 5) & 1) * 64, b = bid >> 6;
        const int tr = tid >> 4, tc = (tid & 15) * 4;
#pragma unroll
        for (int it = 0; it < 4; ++it) {
            int r = it * 16 + tr;
            *(ushort4*)&tile[r][tc] = *(const ushort4*)(g1 + (size_t)(b * SS + s0 + r) * 320 + d0 + tc);
        }
        __syncthreads();
#pragma unroll
        for (int it = 0; it < 4; ++it) {
            int r = it * 16 + tr;
            int d = d0 + r;
            ushort4 o;
            o.x = tile[tc][r]; o.y = tile[tc + 1][r]; o.z = tile[tc + 2][r]; o.w = tile[tc + 3][r];
            int chunk = tc >> 3;
            int col = ((chunk ^ (d & 7)) << 3) + (tc & 7);
            *(ushort4*)(ckv_t + ((size_t)b * 128 + d) * 2048 + s0 + col) = o;
        }
    } else if (bid < 640) {                 // rope_k: NTOK*32 elements
        int i = (bid - 128) * 256 + tid;
        int j = i & 31, row = i >> 5;
        int pos = row & (SS - 1);
        float2 cs = tab[(pos << 5) | j];
        unsigned short* p = g1 + (size_t)row * 320 + 256 + 2 * j;
        float x0 = bf2f(p[0]), x1 = bf2f(p[1]);
        p[0] = f2bf(x0 * cs.x - x1 * cs.y);
        p[1] = f2bf(x0 * cs.y + x1 * cs.x);
    } else {                                // q-projection with fused rope epilogue
        const int t0 = bid - 640;
        const int by = t0 / 24, bx = t0 - by * 24;
        constexpr int BK = 32;
        const int wave = tid >> 6, lane = tid & 63;
        const int wr = wave >> 1, wc = wave & 1;
        const int lg = lane >> 4, lr = lane & 15;
        const int m0 = by * 128, n0 = bx * 128;
        f32x4 acc[4][4] = {};
        auto stage = [&](int k0, int buf) {
#pragma unroll
            for (int it = 0; it < 2; ++it) {
                int e = (tid + it * 256) * 8;          // 4096 elems: A rows 0..127
                GLOAD_LDS16(Aq + (size_t)(m0 + (e >> 5)) * 320 + k0 + (e & 31), &sm[buf][0][0] + e);
            }
#pragma unroll
            for (int it = 0; it < 2; ++it) {
                int e = (tid + it * 256) * 8;          // 4096 elems: B rows 0..127 at offset 4096
                GLOAD_LDS16(Btq + (size_t)(n0 + (e >> 5)) * 128 + k0 + (e & 31), &sm[buf][128][0] + e);
            }
        };
        auto rdA = [&](int buf, int r, int c) -> short8 {
            return *(const short8*)(&sm[buf][0][0] + r * 32 + c);
        };
        auto rdB = [&](int buf, int r, int c) -> short8 {
            return *(const short8*)(&sm[buf][128][0] + r * 32 + c);
        };
        stage(0, 0);
        __syncthreads();
        for (int t = 0; t < 4; ++t) {
            const int cur = t & 1;
            if (t + 1 < 4) stage((t + 1) * BK, cur ^ 1);
            short8 af[4], bfr[4];
#pragma unroll
            for (int i = 0; i < 4; i++) af[i] = rdA(cur, wr * 64 + i * 16 + lr, lg * 8);
#pragma unroll
            for (int j = 0; j < 4; j++) bfr[j] = rdB(cur, wc * 64 + j * 16 + lr, lg * 8);
#pragma unroll
            for (int i = 0; i < 4; i++)
#pragma unroll
                for (int j = 0; j < 4; j++)
                    acc[i][j] = __builtin_amdgcn_mfma_f32_16x16x32_bf16(af[i], bfr[j], acc[i][j], 0, 0, 0);
            __syncthreads();
        }
#pragma unroll
        for (int i = 0; i < 4; i++)
#pragma unroll
            for (int j = 0; j < 4; j++) {
                const int colb = n0 + wc * 64 + j * 16;
                const int c6 = colb >> 6;
                const int h = (c6 * 43) >> 7;
                const int ch = colb - h * 192;
#pragma unroll
                for (int r = 0; r < 4; r++) {
                    int row = m0 + wr * 64 + i * 16 + lg * 4 + r;
                    int col = colb + lr;
                    float val = acc[i][j][r];
                    if (ch >= 128) {
                        float partner = __shfl_xor(val, 1);
                        int jr = (ch + lr - 128) >> 1;
                        float2 cs = tab[((row & (SS - 1)) << 5) | jr];
                        val = (lr & 1) ? (partner * cs.y + val * cs.x)
                                       : (val * cs.x - partner * cs.y);
                    }
                    C[(size_t)row * QSTR + col] = f2bf(val);
                }
            }
    }
}

// ---------------- out-proj: 128x256 deep-pipelined GEMM (T2+T3+T4+T5) ----------------
__global__ __launch_bounds__(512, 2) void gemm_out_kernel(
    const unsigned short* __restrict__ Ag,     // attn [4096][2048]
    const unsigned short* __restrict__ Bg,     // WeffT [2048][2048]
    float* __restrict__ C) {
    __shared__ __align__(16) unsigned short As[3][128][64];
    __shared__ __align__(16) unsigned short Bs[3][256][64];
    const int tid = threadIdx.x, wave = tid >> 6, lane = tid & 63;
    const int wr = wave >> 2, wc = wave & 3;
    const int lg = lane >> 4, lr = lane & 15;
    int id = blockIdx.y * gridDim.x + blockIdx.x;      // grid (8, 32) = 256
    int swz = (id & 7) * 32 + (id >> 3);               // bijective XCD grouping
    const int n0 = (swz & 7) * 256;
    const int m0 = (swz >> 3) * 128;

    f32x4 acc[4][4] = {};

    auto STAGE = [&](int kt, int buf) {
        const int k0 = kt * 64;
#pragma unroll
        for (int it = 0; it < 2; ++it) {               // A: 128 rows x 8 chunks
            int cid = tid + it * 512;
            int row = cid >> 3, slot = cid & 7;
            int csrc = slot ^ (row & 7);
            GLOAD_LDS16(Ag + (size_t)(m0 + row) * 2048 + k0 + csrc * 8, &As[buf][0][0] + cid * 8);
        }
#pragma unroll
        for (int it = 0; it < 4; ++it) {               // B: 256 rows x 8 chunks
            int cid = tid + it * 512;
            int row = cid >> 3, slot = cid & 7;
            int csrc = slot ^ (row & 7);
            GLOAD_LDS16(Bg + (size_t)(n0 + row) * 2048 + k0 + csrc * 8, &Bs[buf][0][0] + cid * 8);
        }
    };
    auto compute = [&](int buf) {
#pragma unroll
        for (int ks = 0; ks < 2; ++ks) {
            const int ca = ((ks * 4 + lg) ^ (lr & 7)) * 8;   // swizzled read chunk
            short8 af[4], bfr[4];
#pragma unroll
            for (int i = 0; i < 4; i++) af[i] = *(const short8*)&As[buf][wr * 64 + i * 16 + lr][ca];
#pragma unroll
            for (int j = 0; j < 4; j++) bfr[j] = *(const short8*)&Bs[buf][wc * 64 + j * 16 + lr][ca];
            __builtin_amdgcn_s_setprio(1);
#pragma unroll
            for (int i = 0; i < 4; i++)
#pragma unroll
                for (int j = 0; j < 4; j++)
                    acc[i][j] = __builtin_amdgcn_mfma_f32_16x16x32_bf16(af[i], bfr[j], acc[i][j], 0, 0, 0);
            __builtin_amdgcn_s_setprio(0);
        }
    };

    STAGE(0, 0); STAGE(1, 1); STAGE(2, 2);             // 18 loads in flight
    for (int t = 0; t < 30; ++t) {
        asm volatile("s_waitcnt vmcnt(12)" ::: "memory");
        __builtin_amdgcn_s_barrier();
        asm volatile("" ::: "memory");
        compute(t % 3);
        asm volatile("" ::: "memory");
        __builtin_amdgcn_s_barrier();
        if (t < 29) STAGE(t + 3, t % 3);
    }
    asm volatile("s_waitcnt vmcnt(6)" ::: "memory");
    __builtin_amdgcn_s_barrier();
    asm volatile("" ::: "memory");
    compute(0);
    asm volatile("" ::: "memory");
    __builtin_amdgcn_s_barrier();
    asm volatile("s_waitcnt vmcnt(0)" ::: "memory");
    __builtin_amdgcn_s_barrier();
    asm volatile("" ::: "memory");
    compute(1);

#pragma unroll
    for (int i = 0; i < 4; i++)
#pragma unroll
        for (int j = 0; j < 4; j++)
#pragma unroll
            for (int r = 0; r < 4; r++) {
                int row = m0 + wr * 64 + i * 16 + lg * 4 + r;
                int col = n0 + wc * 64 + j * 16 + lr;
                C[(size_t)row * 2048 + col] = acc[i][j][r];
            }
}

// ---------------- flash attention v10: 3-buffer counted-vmcnt pipeline ----------------
__global__ __launch_bounds__(512) void mla_attn_kernel(
    const unsigned short* __restrict__ q_all,   // [NTOK][3072]: per head [qtil(128)|qrope(64)]
    const unsigned short* __restrict__ g1,      // [NTOK][320]: ckv 0..127, roped k_r 256..319
    const unsigned short* __restrict__ ckv_t,   // [2][128][2048] chunk-swizzled
    unsigned short* __restrict__ attn_out,      // [NTOK][2048] (o_lat)
    unsigned short* __restrict__ partOb,        // [256 pair][2 side][128 q][128 d] bf16
    float* __restrict__ partL,
    float* __restrict__ partM) {
    __shared__ __align__(16) char smem[122880];
    auto Ks = (unsigned short (*)[64][192])smem;             // [3][64][192], chunk-swizzled
    auto Vs = (unsigned short (*)[128][64])(smem + 73728);   // [3][128][64], chunk-swizzled

    const int id = blockIdx.x;
    const int xcd = id & 7, loc = id >> 3;
    const int hp = 2 * xcd + (loc >> 4);        // head-pair 0..15
    const int s2 = loc & 15;
    const bool roleA = s2 < 8;
    const int qb = roleA ? s2 : s2 - 8;
    const int hiqb = 15 - qb, xsp = 15 - 2 * qb;
    const int b = hp >> 3;
    const int tid = threadIdx.x, wave = tid >> 6, lane = tid & 63;
    const int wg = wave & 3, hsel = wave >> 2;
    const int h = (hp & 7) * 2 + hsel;
    const int bh = b * 16 + h;
    const int pairIdx = bh * 8 + qb;
    const int ql = lane & 31, hb = lane >> 5;
    const int kvB = b * SS;
    const float sc2 = 0.12751744f;   // (1/sqrt(128)) * log2(e)
    const int xh = ql & 7;

    auto stageK = [&](int t, int bufi) {       // 3 gload_lds / thread
#pragma unroll
        for (int it = 0; it < 3; ++it) {
            int cid = tid + it * 512;
            int r = cid / 24, s = cid - r * 24;
            int c = s ^ (r & 7);
            int col = (c < 16) ? c * 8 : 256 + (c - 16) * 8;
            GLOAD_LDS16(g1 + (size_t)(kvB + t * 64 + r) * 320 + col,
                        &Ks[bufi][0][0] + cid * 8);
        }
    };
    auto stageV = [&](int t, int bufi) {       // 2 gload_lds / thread (src pre-swizzled)
#pragma unroll
        for (int it = 0; it < 2; ++it) {
            int e = tid * 8 + it * 4096;
            GLOAD_LDS16(ckv_t + ((size_t)b * 128 + (e >> 6)) * 2048 + t * 64 + (e & 63),
                        &Vs[bufi][0][0] + e);
        }
    };

    auto run = [&](int q0, int t0, int cnt, bool direct, int side) {
        __syncthreads();                       // fence prior smem use (drains prior vmem too)
        const int q0w = q0 + wg * 32;
        const int qg = q0w + ql;

        short8 qf[12];
        {
            const unsigned short* qp = q_all + (size_t)(kvB + qg) * QSTR + h * HD2 + hb * 8;
#pragma unroll
            for (int ss = 0; ss < 12; ++ss) qf[ss] = *(const short8*)(qp + 16 * ss);
        }
        f32x16 o[4] = {};
        float m_raw = -3e38f, mb = 0.f, l_r = 0.f;

        stageK(t0, 0); stageV(t0, 0);
        if (cnt > 1) { stageK(t0 + 1, 1); stageV(t0 + 1, 1); }
        if (cnt > 2) { stageK(t0 + 2, 2); stageV(t0 + 2, 2); }

        for (int tt = 0; tt < cnt; ++tt) {
            const int t = t0 + tt;
            const int cur = tt % 3;
            int ahead = cnt - tt - 1; if (ahead > 2) ahead = 2;
            if (ahead == 2)      asm volatile("s_waitcnt vmcnt(10)" ::: "memory");
            else if (ahead == 1) asm volatile("s_waitcnt vmcnt(5)" ::: "memory");
            else                 asm volatile("s_waitcnt vmcnt(0)" ::: "memory");
            __builtin_amdgcn_s_barrier();       // tile tt landed for ALL waves
            asm volatile("" ::: "memory");
            {
                f32x16 p0 = {}, p1 = {};
                __builtin_amdgcn_s_setprio(1);
#pragma unroll
                for (int ss = 0; ss < 12; ++ss) {
                    int pc = (((2 * ss + hb) ^ xh) << 3);
                    short8 k0 = *(const short8*)&Ks[cur][ql][pc];
                    short8 k1 = *(const short8*)&Ks[cur][32 + ql][pc];
                    p0 = __builtin_amdgcn_mfma_f32_32x32x16_bf16(k0, qf[ss], p0, 0, 0, 0);
                    p1 = __builtin_amdgcn_mfma_f32_32x32x16_bf16(k1, qf[ss], p1, 0, 0, 0);
                }
                __builtin_amdgcn_s_setprio(0);
                const int kv0 = t * 64;
                if (kv0 + 63 > q0w) {
#pragma unroll
                    for (int r = 0; r < 16; ++r) {
                        int kvg = kv0 + (r & 3) + 8 * (r >> 2) + 4 * hb;
                        if (kvg > qg) p0[r] = -3e38f;
                        if (kvg + 32 > qg) p1[r] = -3e38f;
                    }
                }
                float pm = -3e38f;
#pragma unroll
                for (int r = 0; r < 16; ++r) pm = fmaxf(pm, fmaxf(p0[r], p1[r]));
                pm = fmaxf(pm, __shfl_xor(pm, 32));
                if (__any(pm > m_raw + 64.f)) {   // defer-max (T13)
                    float mn = fmaxf(m_raw, pm);
                    float alpha = exp2f((m_raw - mn) * sc2);
                    m_raw = mn; mb = mn * sc2;
                    l_r *= alpha;
#pragma unroll
                    for (int dt = 0; dt < 4; ++dt)
#pragma unroll
                        for (int r = 0; r < 16; ++r) o[dt][r] *= alpha;
                }
                float ps = 0.f;
#pragma unroll
                for (int r = 0; r < 16; ++r) {
                    p0[r] = exp2f(__builtin_fmaf(p0[r], sc2, -mb));
                    p1[r] = exp2f(__builtin_fmaf(p1[r], sc2, -mb));
                    ps += p0[r] + p1[r];
                }
                l_r += ps;
                unsigned int pk0[8], pk1[8];
#pragma unroll
                for (int i = 0; i < 8; ++i) {
                    asm("v_cvt_pk_bf16_f32 %0, %1, %2" : "=v"(pk0[i]) : "v"(p0[2 * i]), "v"(p0[2 * i + 1]));
                    asm("v_cvt_pk_bf16_f32 %0, %1, %2" : "=v"(pk1[i]) : "v"(p1[2 * i]), "v"(p1[2 * i + 1]));
                }
                uint4 bfr[4];
#pragma unroll
                for (int sg = 0; sg < 2; ++sg) {
                    unsigned int x0 = pk0[4 * sg], y0 = pk0[4 * sg + 2];
                    asm volatile("v_permlane32_swap_b32 %0, %1" : "+v"(x0), "+v"(y0));
                    unsigned int x1 = pk0[4 * sg + 1], y1 = pk0[4 * sg + 3];
                    asm volatile("v_permlane32_swap_b32 %0, %1" : "+v"(x1), "+v"(y1));
                    bfr[sg] = make_uint4(x0, x1, y0, y1);
                    unsigned int x2 = pk1[4 * sg], y2 = pk1[4 * sg + 2];
                    asm volatile("v_permlane32_swap_b32 %0, %1" : "+v"(x2), "+v"(y2));
                    unsigned int x3 = pk1[4 * sg + 1], y3 = pk1[4 * sg + 3];
                    asm volatile("v_permlane32_swap_b32 %0, %1" : "+v"(x3), "+v"(y3));
                    bfr[2 + sg] = make_uint4(x2, x3, y2, y3);
                }
                __builtin_amdgcn_s_setprio(1);
#pragma unroll
                for (int ss = 0; ss < 4; ++ss) {
                    short8 pb = __builtin_bit_cast(short8, bfr[ss]);
                    int vc = (((2 * ss + hb) ^ xh) << 3);
#pragma unroll
                    for (int dt = 0; dt < 4; ++dt) {
                        short8 vf = *(const short8*)&Vs[cur][dt * 32 + ql][vc];
                        o[dt] = __builtin_amdgcn_mfma_f32_32x32x16_bf16(vf, pb, o[dt], 0, 0, 0);
                    }
                }
                __builtin_amdgcn_s_setprio(0);
            }
            asm volatile("" ::: "memory");
            __builtin_amdgcn_s_barrier();       // all waves done reading buf cur
            if (tt + 3 < cnt) { stageK(t + 3, cur); stageV(t + 3, cur); }
        }

        l_r += __shfl_xor(l_r, 32);
        if (direct) {
            float inv_l = 1.f / l_r;
            unsigned int* ep = (unsigned int*)smem + wave * 2176;
#pragma unroll
            for (int dt = 0; dt < 4; ++dt)
#pragma unroll
                for (int r = 0; r < 16; r += 2) {
                    float a = o[dt][r] * inv_l, c2 = o[dt][r + 1] * inv_l;
                    unsigned int pkv;
                    asm("v_cvt_pk_bf16_f32 %0, %1, %2" : "=v"(pkv) : "v"(a), "v"(c2));
                    ep[ql * 68 + dt * 16 + ((r & 3) >> 1) + 4 * (r >> 2) + 2 * hb] = pkv;
                }
#pragma unroll
            for (int it = 0; it < 8; ++it) {
                int qr = lane >> 1, ch = (lane & 1) * 8 + it;
                uint4 w = *(uint4*)&ep[qr * 68 + ch * 4];
                *(uint4*)(attn_out + (size_t)(kvB + q0w + qr) * 2048 + h * 128 + ch * 8) = w;
            }
        } else {
            float* sW = (float*)smem + wg * 4224;
            const size_t pb2 = ((size_t)pairIdx * 2 + side);
#pragma unroll
            for (int pass = 0; pass < 2; ++pass) {
                if (pass == 1) __syncthreads();
                if (hsel == pass) {
#pragma unroll
                    for (int dt = 0; dt < 4; ++dt)
#pragma unroll
                        for (int r = 0; r < 16; ++r)
                            sW[ql * 132 + dt * 32 + (r & 3) + 8 * (r >> 2) + 4 * hb] = o[dt][r];
                    int q = lane >> 1, half = lane & 1;
                    const float* src = sW + q * 132 + half * 64;
                    unsigned int* dst = (unsigned int*)(partOb + pb2 * 16384 + ((size_t)(wg * 32 + q)) * 128 + half * 64);
#pragma unroll
                    for (int j = 0; j < 64; j += 4) {
                        float4 f = *(const float4*)(src + j);
                        unsigned int d0, d1;
                        asm("v_cvt_pk_bf16_f32 %0, %1, %2" : "=v"(d0) : "v"(f.x), "v"(f.y));
                        asm("v_cvt_pk_bf16_f32 %0, %1, %2" : "=v"(d1) : "v"(f.z), "v"(f.w));
                        *(uint2*)(dst + (j >> 1)) = make_uint2(d0, d1);
                    }
                    if (hb == 0) {
                        partL[pb2 * 128 + wg * 32 + ql] = l_r;
                        partM[pb2 * 128 + wg * 32 + ql] = m_raw;
                    }
                }
            }
        }
    };

    if (roleA) {
        run(qb * 128, 0, 2 * qb + 2, true, 0);
        run(hiqb * 128, 0, xsp, false, 0);
    } else {
        run(hiqb * 128, xsp, 17, false, 1);
    }
}

// merge the two partials of each hi q-tile (bf16 partO)
__global__ __launch_bounds__(256) void merge_kernel(
    const unsigned short* __restrict__ partOb, const float* __restrict__ partL,
    const float* __restrict__ partM, unsigned short* __restrict__ attn_out) {
    __shared__ float sA[128], sB[128], sI[128];
    const int p = blockIdx.x, tid = threadIdx.x;
    const int bh = p >> 3, qb = p & 7;
    const int b = bh >> 4, h = bh & 15;
    const int q0 = (15 - qb) * 128;
    const float sc2 = 0.12751744f;
    if (tid < 128) {
        float mA = partM[(size_t)(p * 2) * 128 + tid];
        float mB = partM[(size_t)(p * 2 + 1) * 128 + tid];
        float mM = fmaxf(mA, mB);
        float aA = exp2f((mA - mM) * sc2), aB = exp2f((mB - mM) * sc2);
        float lT = aA * partL[(size_t)(p * 2) * 128 + tid] + aB * partL[(size_t)(p * 2 + 1) * 128 + tid];
        sA[tid] = aA; sB[tid] = aB; sI[tid] = 1.f / lT;
    }
    __syncthreads();
    const int q = tid >> 1, half = tid & 1;
    const float aA = sA[q], aB = sB[q], inv = sI[q];
    const unsigned short* oA = partOb + (size_t)(p * 2) * 16384 + q * 128 + half * 64;
    const unsigned short* oB = partOb + (size_t)(p * 2 + 1) * 16384 + q * 128 + half * 64;
    unsigned short* dst = attn_out + (size_t)(b * SS + q0 + q) * 2048 + h * 128 + half * 64;
#pragma unroll
    for (int j = 0; j < 64; j += 4) {
        ushort4 ua = *(const ushort4*)(oA + j);
        ushort4 ub = *(const ushort4*)(oB + j);
        ushort4 u;
        u.x = f2bf((aA * bf2f(ua.x) + aB * bf2f(ub.x)) * inv);
        u.y = f2bf((aA * bf2f(ua.y) + aB * bf2f(ub.y)) * inv);
        u.z = f2bf((aA * bf2f(ua.z) + aB * bf2f(ub.z)) * inv);
        u.w = f2bf((aA * bf2f(ua.w) + aB * bf2f(ub.w)) * inv);
        *(ushort4*)(dst + j) = u;
    }
}

// ---------------- launcher ----------------

extern "C" void kernel_launch(void* const* d_in, const int* in_sizes, int n_in,
                              void* d_out, int out_size, void* d_ws, size_t ws_size,
                              hipStream_t stream) {
    const float* x     = (const float*)d_in[0];
    const float* W_dkv = (const float*)d_in[1];
    const float* W_dq  = (const float*)d_in[2];
    const float* W_kr  = (const float*)d_in[3];
    const float* W_qc  = (const float*)d_in[4];
    const float* W_qr  = (const float*)d_in[5];
    const float* W_uk  = (const float*)d_in[6];
    const float* W_uv  = (const float*)d_in[7];
    const float* W_o   = (const float*)d_in[8];
    float* out = (float*)d_out;

    size_t off = 0;
    auto alloc = [&](size_t bytes) {
        void* p = (char*)d_ws + off;
        off = (off + bytes + 255) & ~(size_t)255;
        return p;
    };
    unsigned short* WcatT = (unsigned short*)alloc((size_t)320 * 2048 * 2);
    unsigned short* Wq2T  = (unsigned short*)alloc((size_t)3072 * 128 * 2);
    unsigned short* WqcB  = (unsigned short*)alloc((size_t)16 * 128 * 64 * 2);
    unsigned short* WukB  = (unsigned short*)alloc((size_t)16 * 128 * 64 * 2);
    unsigned short* WuvB  = (unsigned short*)alloc((size_t)16 * 128 * 128 * 2);
    unsigned short* WoT   = (unsigned short*)alloc((size_t)2048 * 2048 * 2);
    unsigned short* WeffT = (unsigned short*)alloc((size_t)2048 * 2048 * 2);
    unsigned short* g1    = (unsigned short*)alloc((size_t)NTOK * 320 * 2);
    unsigned short* q_all = (unsigned short*)alloc((size_t)NTOK * QSTR * 2);
    unsigned short* ckv_t = (unsigned short*)alloc((size_t)2 * 128 * 2048 * 2);
    unsigned short* attn  = (unsigned short*)alloc((size_t)NTOK * 2048 * 2);
    float2* rope_tab      = (float2*)alloc((size_t)SS * 32 * sizeof(float2));
    unsigned short* partOb= (unsigned short*)alloc((size_t)256 * 2 * 16384 * 2);
    float* partL          = (float*)alloc((size_t)256 * 2 * 128 * 4);
    float* partM          = (float*)alloc((size_t)256 * 2 * 128 * 4);
    float* latP           = (float*)alloc((size_t)2 * NTOK * 320 * 4);

    // 1: layouts (all-coalesced) + rope table
    prep_kernel<<<1984, 256, 0, stream>>>(W_dkv, W_dq, W_kr, W_qc, W_qr, W_uk, W_uv, W_o,
                                          WcatT, Wq2T, WqcB, WukB, WuvB, WoT, rope_tab);
    // 2: absorbed-weight precomputes + latent split-K GEMM (fused)
    fused2_kernel<<<912, 256, 0, stream>>>(WqcB, WukB, Wq2T, WoT, WuvB, WeffT, x, WcatT, latP);
    // 3: split-K reduce
    lat_reduce_kernel<<<NTOK * 320 / 1024, 256, 0, stream>>>(latP, g1);
    // 4: ckv transpose (pre-swizzled) + k-rope + q-projection (fused)
    fused3_kernel<<<1408, 256, 0, stream>>>(g1, ckv_t, rope_tab, g1 + 128, Wq2T, q_all);
    // 5: attention (3-buffer counted-vmcnt pipeline) + merge
    mla_attn_kernel<<<256, 512, 0, stream>>>(q_all, g1, ckv_t, attn, partOb, partL, partM);
    merge_kernel<<<256, 256, 0, stream>>>(partOb, partL, partM, attn);
    // 6: output projection with W_eff -> fp32 (deep-pipelined)
    gemm_out_kernel<<<dim3(8, 32), 512, 0, stream>>>(attn, WeffT, out);
}